// Round 3
// baseline (3129.687 us; speedup 1.0000x reference)
//
#include <hip/hip_runtime.h>
#include <hip/hip_bf16.h>

#define B_     8
#define CIN_   2
#define N_     512
#define C_     32
#define L_     64
#define LOUT_  61
#define BUF_   ((size_t)(8*32*512*64))   // 8,388,608 elements per scratch buffer (bf16)

typedef __hip_bfloat16 bf16;
static __device__ __forceinline__ float b2f(bf16 v) { return __bfloat162float(v); }
static __device__ __forceinline__ bf16  f2b(float v) { return __float2bfloat16(v); }

// ---------------- K0: start 1x1 conv: h[b,o,n,l] = sum_c x[b,c,n,l]*W[o,c] + b[o]
__global__ void k_start(const float* __restrict__ x,
                        const float* __restrict__ Wst,
                        const float* __restrict__ bst,
                        bf16* __restrict__ h) {
    int idx = blockIdx.x * 256 + threadIdx.x;          // covers BUF_ exactly
    int l = idx & 63;
    int n = (idx >> 6) & 511;
    int o = (idx >> 15) & 31;
    int b = idx >> 20;
    int base = (b * CIN_ * N_ + n) * L_ + l;           // c=0
    float acc = bst[o]
              + x[base] * Wst[o * 2 + 0]
              + x[base + N_ * L_] * Wst[o * 2 + 1];
    h[idx] = f2b(acc);
}

// ---------------- K1: gated temporal conv (kernel (1,2), dilation 1)
__global__ void k_gated(const bf16* __restrict__ h,
                        const float* __restrict__ Wf, const float* __restrict__ bfp,
                        const float* __restrict__ Wg, const float* __restrict__ bgp,
                        bf16* __restrict__ G, int Llen) {
    __shared__ float hs[C_][L_];        // 8 KB
    __shared__ float wf[C_][C_][2];     // 8 KB
    __shared__ float wg[C_][C_][2];     // 8 KB
    __shared__ float bfs[C_], bgs[C_];
    int b = blockIdx.x >> 9;
    int n = blockIdx.x & 511;
    int t = threadIdx.x;
    for (int e = t; e < C_ * C_ * 2; e += 256) {
        ((float*)wf)[e] = Wf[e];
        ((float*)wg)[e] = Wg[e];
    }
    if (t < C_) { bfs[t] = bfp[t]; bgs[t] = bgp[t]; }
    for (int e = t; e < C_ * L_; e += 256) {
        int c = e >> 6, l = e & 63;
        hs[c][l] = (l < Llen) ? b2f(h[((size_t)(b * C_ + c) * N_ + n) * L_ + l]) : 0.f;
    }
    __syncthreads();
    int l = t & 63;
    int ob = t >> 6;
    if (l < Llen - 1) {
        for (int j = 0; j < 8; ++j) {
            int o = ob + 4 * j;
            float f = bfs[o], g = bgs[o];
            #pragma unroll
            for (int c = 0; c < C_; ++c) {
                float h0 = hs[c][l], h1 = hs[c][l + 1];
                f += h0 * wf[o][c][0] + h1 * wf[o][c][1];
                g += h0 * wg[o][c][0] + h1 * wg[o][c][1];
            }
            float gv = tanhf(f) * (1.0f / (1.0f + expf(-g)));
            G[((size_t)(b * C_ + o) * N_ + n) * L_ + l] = f2b(gv);
        }
    }
}

// ---------------- K2: skip 1x1 conv, accumulated directly into d_out [b,l,n,c] (fp32)
// mode 0: init (depth 0), 1: add (depth 1), 2: add + output BN (depth 2)
__global__ void k_skip_out(const bf16* __restrict__ G,
                           const float* __restrict__ Wsk, const float* __restrict__ bsk,
                           float* __restrict__ out, int off, int mode,
                           const float* __restrict__ og, const float* __restrict__ obb) {
    __shared__ float gs[C_][L_];
    __shared__ float wsm[C_][C_];
    __shared__ float bs[C_];
    int b = blockIdx.x >> 9;
    int n = blockIdx.x & 511;
    int t = threadIdx.x;
    for (int e = t; e < C_ * C_; e += 256) ((float*)wsm)[e] = Wsk[e];
    if (t < C_) bs[t] = bsk[t];
    for (int e = t; e < C_ * L_; e += 256) {
        int c = e >> 6, l = e & 63;
        gs[c][l] = b2f(G[((size_t)(b * C_ + c) * N_ + n) * L_ + l]);
    }
    __syncthreads();
    int l = t & 63;
    int ob = t >> 6;
    if (l < LOUT_) {
        const float r = rsqrtf(1.0f + 1e-5f);
        for (int j = 0; j < 8; ++j) {
            int o = ob + 4 * j;
            float s = bs[o];
            #pragma unroll
            for (int c = 0; c < C_; ++c) s += gs[c][l + off] * wsm[o][c];
            size_t oi = ((size_t)(b * LOUT_ + l) * N_ + n) * C_ + o;
            if (mode == 0) {
                out[oi] = s;
            } else {
                float v = out[oi] + s;
                if (mode == 2) v = v * (og[o] * r) + obb[o];
                out[oi] = v;
            }
        }
    }
}

// ---------------- K3: graph diffusion  Y[b,c,m,l] = sum_n X[b,c,n,l] * adj[n,m]
__global__ void k_diffuse(const bf16* __restrict__ X, const float* __restrict__ adj,
                          bf16* __restrict__ Y, int lw) {
    __shared__ float As[32][33];        // [m_local][n_local], padded
    __shared__ float Gs[4][32][64];     // [c_local][n_local][l]  32 KB
    int mt = blockIdx.x & 15;
    int cg = (blockIdx.x >> 4) & 7;
    int b  = blockIdx.x >> 7;
    int t = threadIdx.x;
    int l = t & 63, wv = t >> 6;
    int m0 = mt * 32;
    float acc[4][8];
    #pragma unroll
    for (int k = 0; k < 4; ++k)
        #pragma unroll
        for (int j = 0; j < 8; ++j) acc[k][j] = 0.f;
    const bf16* Xb = X + (size_t)(b * C_ + cg * 4) * N_ * L_;
    for (int n0 = 0; n0 < N_; n0 += 32) {
        __syncthreads();
        for (int e = t; e < 1024; e += 256) {
            int i = e >> 5, j = e & 31;
            As[j][i] = adj[(n0 + i) * N_ + m0 + j];
        }
        for (int e = t; e < 4 * 32 * 64; e += 256) {
            int c = e >> 11;
            int i = (e >> 6) & 31;
            int ll = e & 63;
            Gs[c][i][ll] = (ll < lw) ? b2f(Xb[((size_t)c * N_ + n0 + i) * L_ + ll]) : 0.f;
        }
        __syncthreads();
        #pragma unroll 4
        for (int i = 0; i < 32; ++i) {
            float g0 = Gs[0][i][l], g1 = Gs[1][i][l], g2 = Gs[2][i][l], g3 = Gs[3][i][l];
            #pragma unroll
            for (int j = 0; j < 8; ++j) {
                float a = As[wv + 4 * j][i];
                acc[0][j] += a * g0;
                acc[1][j] += a * g1;
                acc[2][j] += a * g2;
                acc[3][j] += a * g3;
            }
        }
    }
    if (l < lw) {
        for (int k = 0; k < 4; ++k)
            for (int j = 0; j < 8; ++j)
                Y[((size_t)(b * C_ + cg * 4 + k) * N_ + m0 + wv + 4 * j) * L_ + l] = f2b(acc[k][j]);
    }
}

// ---------------- K4: full graph-conv + gcBN + residual + BN, writes new h IN PLACE over G.
// newh[o][l] = bn2( bn1( bgc[o] + sum_c W[o,c]g + W[o,32+c]x1 + W[o,64+c]x2 ) + hres[o][l+1] )
__global__ void k_gc3(bf16* __restrict__ G, const bf16* __restrict__ X1,
                      const bf16* __restrict__ X2, const bf16* __restrict__ hres,
                      const float* __restrict__ Wgc, const float* __restrict__ bgc,
                      const float* __restrict__ gg, const float* __restrict__ gb,
                      const float* __restrict__ bg2, const float* __restrict__ bb2,
                      int lw) {
    __shared__ float gs[C_][L_];
    __shared__ float x1s[C_][L_];
    __shared__ float x2s[C_][L_];
    __shared__ float hs[C_][L_];
    __shared__ float wsm[C_][96];
    __shared__ float bs[C_];
    int b = blockIdx.x >> 9;
    int n = blockIdx.x & 511;
    int t = threadIdx.x;
    for (int e = t; e < C_ * 96; e += 256) ((float*)wsm)[e] = Wgc[e];
    if (t < C_) bs[t] = bgc[t];
    for (int e = t; e < C_ * L_; e += 256) {
        int c = e >> 6, l = e & 63;
        size_t gi = ((size_t)(b * C_ + c) * N_ + n) * L_ + l;
        gs[c][l]  = b2f(G[gi]);
        x1s[c][l] = b2f(X1[gi]);
        x2s[c][l] = b2f(X2[gi]);
        hs[c][l]  = b2f(hres[gi]);
    }
    __syncthreads();
    int l = t & 63;
    int ob = t >> 6;
    const float r = rsqrtf(1.0f + 1e-5f);
    if (l < lw) {
        for (int j = 0; j < 8; ++j) {
            int o = ob + 4 * j;
            float s = bs[o];
            #pragma unroll
            for (int c = 0; c < C_; ++c)
                s += gs[c][l] * wsm[o][c] + x1s[c][l] * wsm[o][32 + c]
                   + x2s[c][l] * wsm[o][64 + c];
            float v = s * (gg[o] * r) + gb[o] + hs[o][l + 1];
            v = v * (bg2[o] * r) + bb2[o];
            G[((size_t)(b * C_ + o) * N_ + n) * L_ + l] = f2b(v);
        }
    }
}

extern "C" void kernel_launch(void* const* d_in, const int* in_sizes, int n_in,
                              void* d_out, int out_size, void* d_ws, size_t ws_size,
                              hipStream_t stream) {
    const float* x      = (const float*)d_in[0];
    const float* adj    = (const float*)d_in[1];
    const float* Wstart = (const float*)d_in[2];
    const float* bstart = (const float*)d_in[3];
    const float* Wf     = (const float*)d_in[4];
    const float* bf_    = (const float*)d_in[5];
    const float* Wg     = (const float*)d_in[6];
    const float* bg     = (const float*)d_in[7];
    const float* Wskip  = (const float*)d_in[8];
    const float* bskip  = (const float*)d_in[9];
    const float* Wgc    = (const float*)d_in[10];
    const float* bgc    = (const float*)d_in[11];
    const float* gcbn_g = (const float*)d_in[12];
    const float* gcbn_b = (const float*)d_in[13];
    const float* bn_g   = (const float*)d_in[14];
    const float* bn_b   = (const float*)d_in[15];
    const float* obn_g  = (const float*)d_in[16];
    const float* obn_b  = (const float*)d_in[17];
    float* out = (float*)d_out;

    // 4 bf16 scratch buffers: exactly 64 MiB total.
    bf16* P0 = (bf16*)d_ws;
    bf16* P1 = P0 + BUF_;
    bf16* P2 = P1 + BUF_;
    bf16* P3 = P2 + BUF_;

    k_start<<<(int)(BUF_ / 256), 256, 0, stream>>>(x, Wstart, bstart, P0);

    bf16* h  = P0;
    bf16* Gb = P1;
    for (int i = 0; i < 3; ++i) {
        int Llen = L_ - i;       // valid input length this depth
        int lw = Llen - 1;       // dconv output length
        k_gated<<<B_ * N_, 256, 0, stream>>>(h, Wf + i * 2048, bf_ + i * 32,
                                             Wg + i * 2048, bg + i * 32, Gb, Llen);
        int mode = (i == 0) ? 0 : ((i == 2) ? 2 : 1);
        k_skip_out<<<B_ * N_, 256, 0, stream>>>(Gb, Wskip + i * 1024, bskip + i * 32,
                                                out, 2 - i, mode, obn_g, obn_b);
        if (i == 2) break;
        k_diffuse<<<1024, 256, 0, stream>>>(Gb, adj, P2, lw);     // x1 = G . adj
        k_diffuse<<<1024, 256, 0, stream>>>(P2, adj, P3, lw);     // x2 = x1 . adj
        k_gc3<<<B_ * N_, 256, 0, stream>>>(Gb, P2, P3, h,
                                           Wgc + i * 3072, bgc + i * 32,
                                           gcbn_g + i * 32, gcbn_b + i * 32,
                                           bn_g + i * 32, bn_b + i * 32, lw);
        bf16* tmp = h; h = Gb; Gb = tmp;   // new h lives where G was
    }
}

// Round 4
// 1062.206 us; speedup vs baseline: 2.9464x; 2.9464x over previous
//
#include <hip/hip_runtime.h>
#include <hip/hip_bf16.h>

#define B_     8
#define CIN_   2
#define N_     512
#define C_     32
#define L_     64
#define LOUT_  61
#define BUF_   ((size_t)(8*32*512*64))   // 8,388,608 bf16 elements per scratch buffer

typedef __hip_bfloat16 bf16;
typedef unsigned short ushort_t;
typedef __attribute__((ext_vector_type(8))) unsigned short us8;

static __device__ __forceinline__ float bits2f(ushort_t u) {
    return __uint_as_float(((unsigned)u) << 16);
}
static __device__ __forceinline__ ushort_t f2bits(float v) {   // RNE bf16 (finite inputs)
    unsigned u = __float_as_uint(v);
    return (ushort_t)((u + 0x7fffu + ((u >> 16) & 1u)) >> 16);
}

// ---------------- K0: start 1x1 conv (2->32 ch). One octet of l per thread.
__global__ void k_start(const float* __restrict__ x,
                        const float* __restrict__ Wst,
                        const float* __restrict__ bst,
                        ushort_t* __restrict__ h) {
    int idx = blockIdx.x * 256 + threadIdx.x;      // octet id, 1,048,576 total
    int l0 = (idx & 7) * 8;
    int n  = (idx >> 3) & 511;
    int o  = (idx >> 12) & 31;
    int b  = idx >> 17;
    float w0 = Wst[o * 2], w1 = Wst[o * 2 + 1], bb = bst[o];
    int xbase = (b * CIN_ * N_ + n) * L_ + l0;
    float va[8], vb[8];
    *(float4*)&va[0] = *(const float4*)(x + xbase);
    *(float4*)&va[4] = *(const float4*)(x + xbase + 4);
    *(float4*)&vb[0] = *(const float4*)(x + xbase + N_ * L_);
    *(float4*)&vb[4] = *(const float4*)(x + xbase + N_ * L_ + 4);
    us8 r;
    #pragma unroll
    for (int k = 0; k < 8; ++k) r[k] = f2bits(bb + va[k] * w0 + vb[k] * w1);
    *(us8*)(h + (size_t)idx * 8) = r;
}

// ---------------- K1: gated temporal conv (kernel (1,2)). thread = (o, l-octet)
__global__ void k_gated(const ushort_t* __restrict__ h,
                        const float* __restrict__ Wf, const float* __restrict__ bfp,
                        const float* __restrict__ Wg, const float* __restrict__ bgp,
                        ushort_t* __restrict__ G, int Llen) {
    __shared__ float hs[C_][L_ + 8];     // col 64 zeroed
    __shared__ float wfT[C_][2][C_];     // [c][tap][o]
    __shared__ float wgT[C_][2][C_];
    __shared__ float bfs[C_], bgs[C_];
    int b = blockIdx.x >> 9, n = blockIdx.x & 511, t = threadIdx.x;
    for (int e = t; e < 2048; e += 256) {          // e as [c][tap][o]
        int c = e >> 6, k = (e >> 5) & 1, o = e & 31;
        wfT[c][k][o] = Wf[o * 64 + c * 2 + k];
        wgT[c][k][o] = Wg[o * 64 + c * 2 + k];
    }
    if (t < C_) { bfs[t] = bfp[t]; bgs[t] = bgp[t]; hs[t][64] = 0.f; }
    {
        int c = t >> 3, l0 = (t & 7) * 8;
        us8 v = *(const us8*)(h + ((size_t)(b * C_ + c) * N_ + n) * L_ + l0);
        #pragma unroll
        for (int k = 0; k < 8; ++k)
            hs[c][l0 + k] = (l0 + k < Llen) ? bits2f(v[k]) : 0.f;
    }
    __syncthreads();
    int o = t >> 3, l0 = (t & 7) * 8;
    float f[8], g[8];
    #pragma unroll
    for (int k = 0; k < 8; ++k) { f[k] = bfs[o]; g[k] = bgs[o]; }
    for (int c = 0; c < C_; ++c) {
        float wf0 = wfT[c][0][o], wf1 = wfT[c][1][o];
        float wg0 = wgT[c][0][o], wg1 = wgT[c][1][o];
        #pragma unroll
        for (int k = 0; k < 8; ++k) {
            float h0 = hs[c][l0 + k], h1 = hs[c][l0 + k + 1];
            f[k] += h0 * wf0 + h1 * wf1;
            g[k] += h0 * wg0 + h1 * wg1;
        }
    }
    us8 r;
    #pragma unroll
    for (int k = 0; k < 8; ++k)
        r[k] = f2bits(tanhf(f[k]) * (1.f / (1.f + expf(-g[k]))));
    *(us8*)(G + ((size_t)(b * C_ + o) * N_ + n) * L_ + l0) = r;   // tail garbage finite, masked by consumers
}

// ---------------- K2: skip 1x1 conv into d_out [b,l,n,c] fp32, float4-vectorized
__global__ void k_skip_out(const ushort_t* __restrict__ G,
                           const float* __restrict__ Wsk, const float* __restrict__ bsk,
                           float* __restrict__ out, int off, int mode,
                           const float* __restrict__ og, const float* __restrict__ obb) {
    __shared__ float gs[C_][L_];
    __shared__ float wsT[C_][C_];        // [c][o]
    __shared__ float bs[C_];
    int b = blockIdx.x >> 9, n = blockIdx.x & 511, t = threadIdx.x;
    for (int e = t; e < 1024; e += 256) {          // e as [c][o]
        int c = e >> 5, o = e & 31;
        wsT[c][o] = Wsk[o * 32 + c];
    }
    if (t < C_) bs[t] = bsk[t];
    {
        int c = t >> 3, l0 = (t & 7) * 8;
        us8 v = *(const us8*)(G + ((size_t)(b * C_ + c) * N_ + n) * L_ + l0);
        #pragma unroll
        for (int k = 0; k < 8; ++k) gs[c][l0 + k] = bits2f(v[k]);
    }
    __syncthreads();
    int oq = (t & 7) * 4;
    int lq = t >> 3;
    const float r = rsqrtf(1.f + 1e-5f);
    #pragma unroll
    for (int half = 0; half < 2; ++half) {
        int l = lq + half * 32;
        if (l >= LOUT_) break;
        float s0 = bs[oq], s1 = bs[oq + 1], s2 = bs[oq + 2], s3 = bs[oq + 3];
        for (int c = 0; c < C_; ++c) {
            float gv = gs[c][l + off];
            s0 += gv * wsT[c][oq];     s1 += gv * wsT[c][oq + 1];
            s2 += gv * wsT[c][oq + 2]; s3 += gv * wsT[c][oq + 3];
        }
        float4* po = (float4*)(out + ((size_t)(b * LOUT_ + l) * N_ + n) * C_ + oq);
        if (mode == 0) {
            *po = make_float4(s0, s1, s2, s3);
        } else {
            float4 old = *po;
            float v0 = old.x + s0, v1 = old.y + s1, v2 = old.z + s2, v3 = old.w + s3;
            if (mode == 2) {
                v0 = v0 * (og[oq] * r) + obb[oq];
                v1 = v1 * (og[oq + 1] * r) + obb[oq + 1];
                v2 = v2 * (og[oq + 2] * r) + obb[oq + 2];
                v3 = v3 * (og[oq + 3] * r) + obb[oq + 3];
            }
            *po = make_float4(v0, v1, v2, v3);
        }
    }
}

// ---------------- K3: graph diffusion  Y[b,c,m,l] = sum_n X[b,c,n,l] * adj[n,m]
__global__ void k_diffuse(const ushort_t* __restrict__ X, const float* __restrict__ adj,
                          ushort_t* __restrict__ Y, int lw) {
    __shared__ float As[32][33];        // [m_local][n_local]
    __shared__ float Gs[4][32][64];     // [c_local][n_local][l]
    int mt = blockIdx.x & 15;
    int cg = (blockIdx.x >> 4) & 7;
    int b  = blockIdx.x >> 7;
    int t = threadIdx.x;
    int l = t & 63, wv = t >> 6;
    int m0 = mt * 32;
    float acc[4][8];
    #pragma unroll
    for (int k = 0; k < 4; ++k)
        #pragma unroll
        for (int j = 0; j < 8; ++j) acc[k][j] = 0.f;
    const ushort_t* Xb = X + (size_t)(b * C_ + cg * 4) * N_ * L_;
    int si = t >> 3, sl0 = (t & 7) * 8;
    for (int n0 = 0; n0 < N_; n0 += 32) {
        __syncthreads();
        for (int e = t; e < 1024; e += 256) {
            int i = e >> 5, j = e & 31;
            As[j][i] = adj[(n0 + i) * N_ + m0 + j];
        }
        #pragma unroll
        for (int c = 0; c < 4; ++c) {
            us8 v = *(const us8*)(Xb + ((size_t)c * N_ + n0 + si) * L_ + sl0);
            #pragma unroll
            for (int k = 0; k < 8; ++k)
                Gs[c][si][sl0 + k] = (sl0 + k < lw) ? bits2f(v[k]) : 0.f;
        }
        __syncthreads();
        #pragma unroll 4
        for (int i = 0; i < 32; ++i) {
            float g0 = Gs[0][i][l], g1 = Gs[1][i][l], g2 = Gs[2][i][l], g3 = Gs[3][i][l];
            #pragma unroll
            for (int j = 0; j < 8; ++j) {
                float a = As[wv + 4 * j][i];
                acc[0][j] += a * g0;
                acc[1][j] += a * g1;
                acc[2][j] += a * g2;
                acc[3][j] += a * g3;
            }
        }
    }
    // write back via LDS for vectorized stores
    __syncthreads();
    #pragma unroll
    for (int k = 0; k < 4; ++k)
        #pragma unroll
        for (int j = 0; j < 8; ++j) Gs[k][wv + 4 * j][l] = acc[k][j];
    __syncthreads();
    {
        int m = t >> 3, l0 = (t & 7) * 8;
        #pragma unroll
        for (int k = 0; k < 4; ++k) {
            us8 r;
            #pragma unroll
            for (int q = 0; q < 8; ++q) r[q] = f2bits(Gs[k][m][l0 + q]);
            *(us8*)(Y + ((size_t)(b * C_ + cg * 4 + k) * N_ + m0 + m) * L_ + l0) = r;
        }
    }
}

// ---------------- K4: graph-conv(96->32) + gcBN + residual + BN, in place over G
__global__ void k_gc3(ushort_t* __restrict__ G, const ushort_t* __restrict__ X1,
                      const ushort_t* __restrict__ X2, const ushort_t* __restrict__ hres,
                      const float* __restrict__ Wgc, const float* __restrict__ bgc,
                      const float* __restrict__ gg, const float* __restrict__ gb,
                      const float* __restrict__ bg2, const float* __restrict__ bb2,
                      int lw) {
    __shared__ float gs[C_][L_];
    __shared__ float x1s[C_][L_];
    __shared__ float x2s[C_][L_];
    __shared__ float hs[C_][L_ + 1];     // col 64 zeroed
    __shared__ float wsT[96][32];        // [ci][o]
    __shared__ float bs[C_];
    int b = blockIdx.x >> 9, n = blockIdx.x & 511, t = threadIdx.x;
    for (int e = t; e < 3072; e += 256) {          // e as [ci][o]
        int ci = e >> 5, o = e & 31;
        wsT[ci][o] = Wgc[o * 96 + ci];
    }
    if (t < C_) { bs[t] = bgc[t]; hs[t][64] = 0.f; }
    {
        int c = t >> 3, l0 = (t & 7) * 8;
        size_t base = ((size_t)(b * C_ + c) * N_ + n) * L_ + l0;
        us8 vg = *(const us8*)(G + base);
        us8 v1 = *(const us8*)(X1 + base);
        us8 v2 = *(const us8*)(X2 + base);
        us8 vh = *(const us8*)(hres + base);
        #pragma unroll
        for (int k = 0; k < 8; ++k) {
            gs[c][l0 + k]  = bits2f(vg[k]);
            x1s[c][l0 + k] = bits2f(v1[k]);
            x2s[c][l0 + k] = bits2f(v2[k]);
            hs[c][l0 + k]  = bits2f(vh[k]);
        }
    }
    __syncthreads();
    int o = t >> 3, l0 = (t & 7) * 8;
    float s[8];
    #pragma unroll
    for (int k = 0; k < 8; ++k) s[k] = bs[o];
    for (int c = 0; c < C_; ++c) {
        float w0 = wsT[c][o], w1 = wsT[32 + c][o], w2 = wsT[64 + c][o];
        #pragma unroll
        for (int k = 0; k < 8; ++k)
            s[k] += gs[c][l0 + k] * w0 + x1s[c][l0 + k] * w1 + x2s[c][l0 + k] * w2;
    }
    const float r = rsqrtf(1.f + 1e-5f);
    float ga = gg[o] * r, gbv = gb[o], ba = bg2[o] * r, bbv = bb2[o];
    us8 outv;
    #pragma unroll
    for (int k = 0; k < 8; ++k) {
        float v = s[k] * ga + gbv + hs[o][l0 + k + 1];
        outv[k] = f2bits(v * ba + bbv);
    }
    *(us8*)(G + ((size_t)(b * C_ + o) * N_ + n) * L_ + l0) = outv;
}

extern "C" void kernel_launch(void* const* d_in, const int* in_sizes, int n_in,
                              void* d_out, int out_size, void* d_ws, size_t ws_size,
                              hipStream_t stream) {
    const float* x      = (const float*)d_in[0];
    const float* adj    = (const float*)d_in[1];
    const float* Wstart = (const float*)d_in[2];
    const float* bstart = (const float*)d_in[3];
    const float* Wf     = (const float*)d_in[4];
    const float* bf_    = (const float*)d_in[5];
    const float* Wg     = (const float*)d_in[6];
    const float* bg     = (const float*)d_in[7];
    const float* Wskip  = (const float*)d_in[8];
    const float* bskip  = (const float*)d_in[9];
    const float* Wgc    = (const float*)d_in[10];
    const float* bgc    = (const float*)d_in[11];
    const float* gcbn_g = (const float*)d_in[12];
    const float* gcbn_b = (const float*)d_in[13];
    const float* bn_g   = (const float*)d_in[14];
    const float* bn_b   = (const float*)d_in[15];
    const float* obn_g  = (const float*)d_in[16];
    const float* obn_b  = (const float*)d_in[17];
    float* out = (float*)d_out;

    // 4 bf16 scratch buffers: exactly 64 MiB total.
    ushort_t* P0 = (ushort_t*)d_ws;
    ushort_t* P1 = P0 + BUF_;
    ushort_t* P2 = P1 + BUF_;
    ushort_t* P3 = P2 + BUF_;

    k_start<<<4096, 256, 0, stream>>>(x, Wstart, bstart, P0);

    ushort_t* h  = P0;
    ushort_t* Gb = P1;
    for (int i = 0; i < 3; ++i) {
        int Llen = L_ - i;       // valid input length this depth
        int lw = Llen - 1;       // dconv output length
        k_gated<<<B_ * N_, 256, 0, stream>>>(h, Wf + i * 2048, bf_ + i * 32,
                                             Wg + i * 2048, bg + i * 32, Gb, Llen);
        int mode = (i == 0) ? 0 : ((i == 2) ? 2 : 1);
        k_skip_out<<<B_ * N_, 256, 0, stream>>>(Gb, Wskip + i * 1024, bskip + i * 32,
                                                out, 2 - i, mode, obn_g, obn_b);
        if (i == 2) break;
        k_diffuse<<<1024, 256, 0, stream>>>(Gb, adj, P2, lw);     // x1 = G . adj
        k_diffuse<<<1024, 256, 0, stream>>>(P2, adj, P3, lw);     // x2 = x1 . adj
        k_gc3<<<B_ * N_, 256, 0, stream>>>(Gb, P2, P3, h,
                                           Wgc + i * 3072, bgc + i * 32,
                                           gcbn_g + i * 32, gcbn_b + i * 32,
                                           bn_g + i * 32, bn_b + i * 32, lw);
        ushort_t* tmp = h; h = Gb; Gb = tmp;   // new h lives where G was
    }
}

// Round 5
// 580.799 us; speedup vs baseline: 5.3886x; 1.8289x over previous
//
#include <hip/hip_runtime.h>
#include <hip/hip_bf16.h>

#define B_     8
#define CIN_   2
#define N_     512
#define C_     32
#define L_     64
#define LOUT_  61
#define BUF_   ((size_t)(8*32*512*64))   // 8,388,608 bf16 elements per scratch buffer

typedef __hip_bfloat16 bf16;
typedef unsigned short ushort_t;
typedef __attribute__((ext_vector_type(8))) unsigned short us8;
typedef __attribute__((ext_vector_type(8))) short bf16x8;
typedef __attribute__((ext_vector_type(4))) float f32x4;

static __device__ __forceinline__ float bits2f(ushort_t u) {
    return __uint_as_float(((unsigned)u) << 16);
}
static __device__ __forceinline__ ushort_t f2bits(float v) {   // RNE bf16 (finite inputs)
    unsigned u = __float_as_uint(v);
    return (ushort_t)((u + 0x7fffu + ((u >> 16) & 1u)) >> 16);
}

// ---------------- K0: start 1x1 conv (2->32 ch). One octet of l per thread.
__global__ void k_start(const float* __restrict__ x,
                        const float* __restrict__ Wst,
                        const float* __restrict__ bst,
                        ushort_t* __restrict__ h) {
    int idx = blockIdx.x * 256 + threadIdx.x;      // octet id, 1,048,576 total
    int l0 = (idx & 7) * 8;
    int n  = (idx >> 3) & 511;
    int o  = (idx >> 12) & 31;
    int b  = idx >> 17;
    float w0 = Wst[o * 2], w1 = Wst[o * 2 + 1], bb = bst[o];
    int xbase = (b * CIN_ * N_ + n) * L_ + l0;
    float va[8], vb[8];
    *(float4*)&va[0] = *(const float4*)(x + xbase);
    *(float4*)&va[4] = *(const float4*)(x + xbase + 4);
    *(float4*)&vb[0] = *(const float4*)(x + xbase + N_ * L_);
    *(float4*)&vb[4] = *(const float4*)(x + xbase + N_ * L_ + 4);
    us8 r;
    #pragma unroll
    for (int k = 0; k < 8; ++k) r[k] = f2bits(bb + va[k] * w0 + vb[k] * w1);
    *(us8*)(h + (size_t)idx * 8) = r;
}

// ---------------- K_T: adjT[m][n] = bf16(adj[n][m]), one-shot 512x512 transpose
__global__ void k_transA(const float* __restrict__ adj, ushort_t* __restrict__ adjT) {
    __shared__ float buf[64][65];
    int ti = blockIdx.x & 7;        // n-tile
    int tj = blockIdx.x >> 3;       // m-tile
    int t = threadIdx.x;
    for (int r = 0; r < 16; ++r) {
        int e = t + 256 * r;
        int rl = e >> 6, cl = e & 63;
        buf[rl][cl] = adj[(size_t)(ti * 64 + rl) * 512 + tj * 64 + cl];
    }
    __syncthreads();
    for (int r = 0; r < 16; ++r) {
        int e = t + 256 * r;
        int ml = e >> 6, nl = e & 63;
        adjT[(size_t)(tj * 64 + ml) * 512 + ti * 64 + nl] = f2bits(buf[nl][ml]);
    }
}

// ---------------- K1: gated temporal conv (kernel (1,2)). thread = (o, l-octet)
__global__ void k_gated(const ushort_t* __restrict__ h,
                        const float* __restrict__ Wf, const float* __restrict__ bfp,
                        const float* __restrict__ Wg, const float* __restrict__ bgp,
                        ushort_t* __restrict__ G, int Llen) {
    __shared__ float hs[C_][L_ + 8];     // col 64 zeroed
    __shared__ float wfT[C_][2][C_];     // [c][tap][o]
    __shared__ float wgT[C_][2][C_];
    __shared__ float bfs[C_], bgs[C_];
    int b = blockIdx.x >> 9, n = blockIdx.x & 511, t = threadIdx.x;
    for (int e = t; e < 2048; e += 256) {          // e as [c][tap][o]
        int c = e >> 6, k = (e >> 5) & 1, o = e & 31;
        wfT[c][k][o] = Wf[o * 64 + c * 2 + k];
        wgT[c][k][o] = Wg[o * 64 + c * 2 + k];
    }
    if (t < C_) { bfs[t] = bfp[t]; bgs[t] = bgp[t]; hs[t][64] = 0.f; }
    {
        int c = t >> 3, l0 = (t & 7) * 8;
        us8 v = *(const us8*)(h + ((size_t)(b * C_ + c) * N_ + n) * L_ + l0);
        #pragma unroll
        for (int k = 0; k < 8; ++k)
            hs[c][l0 + k] = (l0 + k < Llen) ? bits2f(v[k]) : 0.f;
    }
    __syncthreads();
    int o = t >> 3, l0 = (t & 7) * 8;
    float f[8], g[8];
    #pragma unroll
    for (int k = 0; k < 8; ++k) { f[k] = bfs[o]; g[k] = bgs[o]; }
    for (int c = 0; c < C_; ++c) {
        float wf0 = wfT[c][0][o], wf1 = wfT[c][1][o];
        float wg0 = wgT[c][0][o], wg1 = wgT[c][1][o];
        #pragma unroll
        for (int k = 0; k < 8; ++k) {
            float h0 = hs[c][l0 + k], h1 = hs[c][l0 + k + 1];
            f[k] += h0 * wf0 + h1 * wf1;
            g[k] += h0 * wg0 + h1 * wg1;
        }
    }
    us8 r;
    #pragma unroll
    for (int k = 0; k < 8; ++k)
        r[k] = f2bits(tanhf(f[k]) * (1.f / (1.f + expf(-g[k]))));
    *(us8*)(G + ((size_t)(b * C_ + o) * N_ + n) * L_ + l0) = r;   // tail garbage bounded (<=1), masked by consumers
}

// ---------------- K2: skip 1x1 conv into d_out [b,l,n,c] fp32, float4-vectorized
__global__ void k_skip_out(const ushort_t* __restrict__ G,
                           const float* __restrict__ Wsk, const float* __restrict__ bsk,
                           float* __restrict__ out, int off, int mode,
                           const float* __restrict__ og, const float* __restrict__ obb) {
    __shared__ float gs[C_][L_];
    __shared__ float wsT[C_][C_];        // [c][o]
    __shared__ float bs[C_];
    int b = blockIdx.x >> 9, n = blockIdx.x & 511, t = threadIdx.x;
    for (int e = t; e < 1024; e += 256) {          // e as [c][o]
        int c = e >> 5, o = e & 31;
        wsT[c][o] = Wsk[o * 32 + c];
    }
    if (t < C_) bs[t] = bsk[t];
    {
        int c = t >> 3, l0 = (t & 7) * 8;
        us8 v = *(const us8*)(G + ((size_t)(b * C_ + c) * N_ + n) * L_ + l0);
        #pragma unroll
        for (int k = 0; k < 8; ++k) gs[c][l0 + k] = bits2f(v[k]);
    }
    __syncthreads();
    int oq = (t & 7) * 4;
    int lq = t >> 3;
    const float r = rsqrtf(1.f + 1e-5f);
    #pragma unroll
    for (int half = 0; half < 2; ++half) {
        int l = lq + half * 32;
        if (l >= LOUT_) break;
        float s0 = bs[oq], s1 = bs[oq + 1], s2 = bs[oq + 2], s3 = bs[oq + 3];
        for (int c = 0; c < C_; ++c) {
            float gv = gs[c][l + off];
            s0 += gv * wsT[c][oq];     s1 += gv * wsT[c][oq + 1];
            s2 += gv * wsT[c][oq + 2]; s3 += gv * wsT[c][oq + 3];
        }
        float4* po = (float4*)(out + ((size_t)(b * LOUT_ + l) * N_ + n) * C_ + oq);
        if (mode == 0) {
            *po = make_float4(s0, s1, s2, s3);
        } else {
            float4 old = *po;
            float v0 = old.x + s0, v1 = old.y + s1, v2 = old.z + s2, v3 = old.w + s3;
            if (mode == 2) {
                v0 = v0 * (og[oq] * r) + obb[oq];
                v1 = v1 * (og[oq + 1] * r) + obb[oq + 1];
                v2 = v2 * (og[oq + 2] * r) + obb[oq + 2];
                v3 = v3 * (og[oq + 3] * r) + obb[oq + 3];
            }
            *po = make_float4(v0, v1, v2, v3);
        }
    }
}

// ---------------- K3: MFMA graph diffusion  Y[b,c,m,l] = sum_n adjT[m][n] * X[b,c,n,l]
// block: (b, m-tile 64, c-pair). 4 waves = (c_loc, l-half). mfma_f32_16x16x32_bf16.
// LDS 16B-block rotation swizzle: blk' = (blk + row>>3)&7 keeps staging b128 and
// frag reads at baseline bank cost.
__global__ void k_diffuse_mfma(const ushort_t* __restrict__ X,
                               const ushort_t* __restrict__ adjT,
                               ushort_t* __restrict__ Y) {
    __shared__ __align__(16) ushort_t lds[12288];  // As[64*64] + Xs[2*64*64]; Ys aliases
    ushort_t* As = lds;
    ushort_t* Xs = lds + 4096;
    int cp = blockIdx.x & 15;          // c-pair (2 channels)
    int mt = (blockIdx.x >> 4) & 7;
    int b  = blockIdx.x >> 7;
    int t  = threadIdx.x;
    int lane = t & 63, w = t >> 6;
    int c_loc = w & 1, lh = w >> 1;
    int m0 = mt * 64;
    int la = lane & 15, q = lane >> 4;
    const ushort_t* Xb = X + (size_t)(b * 32 + cp * 2) * 512 * 64;
    f32x4 acc[4][2];
    #pragma unroll
    for (int mi = 0; mi < 4; ++mi)
        #pragma unroll
        for (int li = 0; li < 2; ++li) acc[mi][li] = (f32x4)0.f;

    for (int n0 = 0; n0 < 512; n0 += 64) {
        __syncthreads();
        #pragma unroll
        for (int r = 0; r < 2; ++r) {              // stage As: adjT[m0..+63][n0..+63]
            int e = t + 256 * r;
            int ml = e >> 3, oct = e & 7;
            us8 v = *(const us8*)(adjT + (size_t)(m0 + ml) * 512 + n0 + oct * 8);
            *(us8*)(As + ml * 64 + (((oct + (ml >> 3)) & 7) << 3)) = v;
        }
        #pragma unroll
        for (int r = 0; r < 4; ++r) {              // stage Xs: [2][64 n][64 l]
            int e = t + 256 * r;
            int cl = e >> 9, nl = (e >> 3) & 63, oct = e & 7;
            us8 v = *(const us8*)(Xb + ((size_t)cl * 512 + n0 + nl) * 64 + oct * 8);
            *(us8*)(Xs + cl * 4096 + nl * 64 + (((oct + (nl >> 3)) & 7) << 3)) = v;
        }
        __syncthreads();
        #pragma unroll
        for (int ks = 0; ks < 2; ++ks) {           // two K=32 steps per chunk
            bf16x8 a[4];
            #pragma unroll
            for (int mi = 0; mi < 4; ++mi) {       // A[m=la][k=q*8+j]
                int m = mi * 16 + la;
                int bl = (ks * 4 + q + (m >> 3)) & 7;
                a[mi] = *(const bf16x8*)(As + m * 64 + bl * 8);
            }
            bf16x8 bb[2];
            #pragma unroll
            for (int li = 0; li < 2; ++li) {       // B[k=q*8+j][n=la]
                int l = lh * 32 + li * 16 + la;
                int rot = ((l >> 3) + ks * 4 + q) & 7;
                int col = rot * 8 + (l & 7);
                const ushort_t* p = Xs + c_loc * 4096 + (ks * 32 + q * 8) * 64 + col;
                bf16x8 v;
                #pragma unroll
                for (int j = 0; j < 8; ++j) v[j] = (short)p[j * 64];
                bb[li] = v;
            }
            #pragma unroll
            for (int mi = 0; mi < 4; ++mi)
                #pragma unroll
                for (int li = 0; li < 2; ++li)
                    acc[mi][li] = __builtin_amdgcn_mfma_f32_16x16x32_bf16(
                        a[mi], bb[li], acc[mi][li], 0, 0, 0);
        }
    }
    __syncthreads();
    ushort_t* Ys = lds;                            // [2][64][72]
    #pragma unroll
    for (int mi = 0; mi < 4; ++mi)
        #pragma unroll
        for (int li = 0; li < 2; ++li)
            #pragma unroll
            for (int r = 0; r < 4; ++r) {          // D: row=q*4+r, col=la
                int row = mi * 16 + q * 4 + r;
                int col = lh * 32 + li * 16 + la;
                Ys[c_loc * 4608 + row * 72 + col] = f2bits(acc[mi][li][r]);
            }
    __syncthreads();
    {
        int c = t >> 7, mrem = t & 127;
        int m = mrem >> 1, lq = mrem & 1;
        #pragma unroll
        for (int r = 0; r < 4; ++r) {
            int l0 = lq * 32 + r * 8;
            us8 v = *(const us8*)(Ys + c * 4608 + m * 72 + l0);
            *(us8*)(Y + ((size_t)(b * 32 + cp * 2 + c) * 512 + m0 + m) * 64 + l0) = v;
        }
    }
}

// ---------------- K4: graph-conv(96->32) + gcBN + residual + BN, in place over G
__global__ void k_gc3(ushort_t* __restrict__ G, const ushort_t* __restrict__ X1,
                      const ushort_t* __restrict__ X2, const ushort_t* __restrict__ hres,
                      const float* __restrict__ Wgc, const float* __restrict__ bgc,
                      const float* __restrict__ gg, const float* __restrict__ gb,
                      const float* __restrict__ bg2, const float* __restrict__ bb2,
                      int lw) {
    __shared__ float gs[C_][L_];
    __shared__ float x1s[C_][L_];
    __shared__ float x2s[C_][L_];
    __shared__ float hs[C_][L_ + 1];     // col 64 zeroed
    __shared__ float wsT[96][32];        // [ci][o]
    __shared__ float bs[C_];
    int b = blockIdx.x >> 9, n = blockIdx.x & 511, t = threadIdx.x;
    for (int e = t; e < 3072; e += 256) {          // e as [ci][o]
        int ci = e >> 5, o = e & 31;
        wsT[ci][o] = Wgc[o * 96 + ci];
    }
    if (t < C_) { bs[t] = bgc[t]; hs[t][64] = 0.f; }
    {
        int c = t >> 3, l0 = (t & 7) * 8;
        size_t base = ((size_t)(b * C_ + c) * N_ + n) * L_ + l0;
        us8 vg = *(const us8*)(G + base);
        us8 v1 = *(const us8*)(X1 + base);
        us8 v2 = *(const us8*)(X2 + base);
        us8 vh = *(const us8*)(hres + base);
        #pragma unroll
        for (int k = 0; k < 8; ++k) {
            gs[c][l0 + k]  = bits2f(vg[k]);
            x1s[c][l0 + k] = bits2f(v1[k]);
            x2s[c][l0 + k] = bits2f(v2[k]);
            hs[c][l0 + k]  = bits2f(vh[k]);
        }
    }
    __syncthreads();
    int o = t >> 3, l0 = (t & 7) * 8;
    float s[8];
    #pragma unroll
    for (int k = 0; k < 8; ++k) s[k] = bs[o];
    for (int c = 0; c < C_; ++c) {
        float w0 = wsT[c][o], w1 = wsT[32 + c][o], w2 = wsT[64 + c][o];
        #pragma unroll
        for (int k = 0; k < 8; ++k)
            s[k] += gs[c][l0 + k] * w0 + x1s[c][l0 + k] * w1 + x2s[c][l0 + k] * w2;
    }
    const float r = rsqrtf(1.f + 1e-5f);
    float ga = gg[o] * r, gbv = gb[o], ba = bg2[o] * r, bbv = bb2[o];
    us8 outv;
    #pragma unroll
    for (int k = 0; k < 8; ++k) {
        float v = s[k] * ga + gbv + hs[o][l0 + k + 1];
        outv[k] = f2bits(v * ba + bbv);
    }
    *(us8*)(G + ((size_t)(b * C_ + o) * N_ + n) * L_ + l0) = outv;
}

extern "C" void kernel_launch(void* const* d_in, const int* in_sizes, int n_in,
                              void* d_out, int out_size, void* d_ws, size_t ws_size,
                              hipStream_t stream) {
    const float* x      = (const float*)d_in[0];
    const float* adj    = (const float*)d_in[1];
    const float* Wstart = (const float*)d_in[2];
    const float* bstart = (const float*)d_in[3];
    const float* Wf     = (const float*)d_in[4];
    const float* bf_    = (const float*)d_in[5];
    const float* Wg     = (const float*)d_in[6];
    const float* bg     = (const float*)d_in[7];
    const float* Wskip  = (const float*)d_in[8];
    const float* bskip  = (const float*)d_in[9];
    const float* Wgc    = (const float*)d_in[10];
    const float* bgc    = (const float*)d_in[11];
    const float* gcbn_g = (const float*)d_in[12];
    const float* gcbn_b = (const float*)d_in[13];
    const float* bn_g   = (const float*)d_in[14];
    const float* bn_b   = (const float*)d_in[15];
    const float* obn_g  = (const float*)d_in[16];
    const float* obn_b  = (const float*)d_in[17];
    float* out = (float*)d_out;

    // 4 bf16 scratch buffers (64 MiB) + adjT bf16 (512 KiB)
    ushort_t* P0   = (ushort_t*)d_ws;
    ushort_t* P1   = P0 + BUF_;
    ushort_t* P2   = P1 + BUF_;
    ushort_t* P3   = P2 + BUF_;
    ushort_t* adjT = P3 + BUF_;

    k_transA<<<64, 256, 0, stream>>>(adj, adjT);
    k_start<<<4096, 256, 0, stream>>>(x, Wstart, bstart, P0);

    ushort_t* h  = P0;
    ushort_t* Gb = P1;
    for (int i = 0; i < 3; ++i) {
        int Llen = L_ - i;       // valid input length this depth
        int lw = Llen - 1;       // dconv output length
        k_gated<<<B_ * N_, 256, 0, stream>>>(h, Wf + i * 2048, bf_ + i * 32,
                                             Wg + i * 2048, bg + i * 32, Gb, Llen);
        int mode = (i == 0) ? 0 : ((i == 2) ? 2 : 1);
        k_skip_out<<<B_ * N_, 256, 0, stream>>>(Gb, Wskip + i * 1024, bskip + i * 32,
                                                out, 2 - i, mode, obn_g, obn_b);
        if (i == 2) break;
        k_diffuse_mfma<<<1024, 256, 0, stream>>>(Gb, adjT, P2);   // x1 = G . adj
        k_diffuse_mfma<<<1024, 256, 0, stream>>>(P2, adjT, P3);   // x2 = x1 . adj
        k_gc3<<<B_ * N_, 256, 0, stream>>>(Gb, P2, P3, h,
                                           Wgc + i * 3072, bgc + i * 32,
                                           gcbn_g + i * 32, gcbn_b + i * 32,
                                           bn_g + i * 32, bn_b + i * 32, lw);
        ushort_t* tmp = h; h = Gb; Gb = tmp;   // new h lives where G was
    }
}

// Round 6
// 498.563 us; speedup vs baseline: 6.2774x; 1.1649x over previous
//
#include <hip/hip_runtime.h>
#include <hip/hip_bf16.h>

#define B_     8
#define CIN_   2
#define N_     512
#define C_     32
#define L_     64
#define LOUT_  61
#define BUF_   ((size_t)(8*32*512*64))   // 8,388,608 bf16 elements per scratch buffer

typedef __hip_bfloat16 bf16;
typedef unsigned short ushort_t;
typedef __attribute__((ext_vector_type(8))) unsigned short us8;
typedef __attribute__((ext_vector_type(8))) short bf16x8;
typedef __attribute__((ext_vector_type(4))) float f32x4;

static __device__ __forceinline__ float bits2f(ushort_t u) {
    return __uint_as_float(((unsigned)u) << 16);
}
static __device__ __forceinline__ ushort_t f2bits(float v) {   // RNE bf16 (finite inputs)
    unsigned u = __float_as_uint(v);
    return (ushort_t)((u + 0x7fffu + ((u >> 16) & 1u)) >> 16);
}

// ---------------- K0: start 1x1 conv (2->32 ch). One octet of l per thread.
__global__ void k_start(const float* __restrict__ x,
                        const float* __restrict__ Wst,
                        const float* __restrict__ bst,
                        ushort_t* __restrict__ h) {
    int idx = blockIdx.x * 256 + threadIdx.x;      // octet id, 1,048,576 total
    int l0 = (idx & 7) * 8;
    int n  = (idx >> 3) & 511;
    int o  = (idx >> 12) & 31;
    int b  = idx >> 17;
    float w0 = Wst[o * 2], w1 = Wst[o * 2 + 1], bb = bst[o];
    int xbase = (b * CIN_ * N_ + n) * L_ + l0;
    float va[8], vb[8];
    *(float4*)&va[0] = *(const float4*)(x + xbase);
    *(float4*)&va[4] = *(const float4*)(x + xbase + 4);
    *(float4*)&vb[0] = *(const float4*)(x + xbase + N_ * L_);
    *(float4*)&vb[4] = *(const float4*)(x + xbase + N_ * L_ + 4);
    us8 r;
    #pragma unroll
    for (int k = 0; k < 8; ++k) r[k] = f2bits(bb + va[k] * w0 + vb[k] * w1);
    *(us8*)(h + (size_t)idx * 8) = r;
}

// ---------------- K_T: adjT[m][n] = bf16(adj[n][m]), one-shot 512x512 transpose
__global__ void k_transA(const float* __restrict__ adj, ushort_t* __restrict__ adjT) {
    __shared__ float buf[64][65];
    int ti = blockIdx.x & 7;        // n-tile
    int tj = blockIdx.x >> 3;       // m-tile
    int t = threadIdx.x;
    for (int r = 0; r < 16; ++r) {
        int e = t + 256 * r;
        int rl = e >> 6, cl = e & 63;
        buf[rl][cl] = adj[(size_t)(ti * 64 + rl) * 512 + tj * 64 + cl];
    }
    __syncthreads();
    for (int r = 0; r < 16; ++r) {
        int e = t + 256 * r;
        int ml = e >> 6, nl = e & 63;
        adjT[(size_t)(tj * 64 + ml) * 512 + ti * 64 + nl] = f2bits(buf[nl][ml]);
    }
}

// ---------------- K1: FUSED gated temporal conv + skip conv + (optional) output BN
// conv phase: thread = (o, l-octet). skip phase: thread = (l, o-octet-of-8... o0=4*8).
__global__ void k_gs(const ushort_t* __restrict__ h,
                     const float* __restrict__ Wf, const float* __restrict__ bfp,
                     const float* __restrict__ Wg, const float* __restrict__ bgp,
                     const float* __restrict__ Wsk, const float* __restrict__ bsk,
                     ushort_t* __restrict__ G, float* __restrict__ out,
                     int Llen, int off, int mode, int storeG,
                     const float* __restrict__ og, const float* __restrict__ obb) {
    __shared__ float hs[32][68];     // stride 68 floats (272B, 16B-aligned rows)
    __shared__ float wfL[32][68];    // row o: Wf[o][ (c,tap) interleaved 64 ]
    __shared__ float wgL[32][68];
    __shared__ float gsT[64][33];    // G transposed [l][c]
    __shared__ float wskT[32][36];   // [c][o]
    __shared__ float bfs[32], bgs[32], bss[32];
    int b = blockIdx.x >> 9, n = blockIdx.x & 511, t = threadIdx.x;

    #pragma unroll
    for (int r = 0; r < 2; ++r) {                  // Wf/Wg: 512 float4 each, linear copy
        int e4 = t + 256 * r;
        int o = e4 >> 4, c4 = (e4 & 15) * 4;
        *(float4*)&wfL[o][c4] = *(const float4*)(Wf + o * 64 + c4);
        *(float4*)&wgL[o][c4] = *(const float4*)(Wg + o * 64 + c4);
    }
    for (int e = t; e < 1024; e += 256) {          // Wsk transpose-stage
        int c = e >> 5, o = e & 31;
        wskT[c][o] = Wsk[o * 32 + c];
    }
    if (t < 32) {
        bfs[t] = bfp[t]; bgs[t] = bgp[t]; bss[t] = bsk[t];
        hs[t][64] = 0.f; hs[t][65] = 0.f; hs[t][66] = 0.f; hs[t][67] = 0.f;
    }
    {
        int c = t >> 3, l0 = (t & 7) * 8;
        us8 v = *(const us8*)(h + ((size_t)(b * 32 + c) * 512 + n) * 64 + l0);
        float tmp[8];
        #pragma unroll
        for (int k = 0; k < 8; ++k) tmp[k] = (l0 + k < Llen) ? bits2f(v[k]) : 0.f;
        *(float4*)&hs[c][l0]     = make_float4(tmp[0], tmp[1], tmp[2], tmp[3]);
        *(float4*)&hs[c][l0 + 4] = make_float4(tmp[4], tmp[5], tmp[6], tmp[7]);
    }
    __syncthreads();

    // ---- conv phase
    {
        int o = t >> 3, l0 = (t & 7) * 8;
        float f[8], g[8];
        #pragma unroll
        for (int k = 0; k < 8; ++k) { f[k] = bfs[o]; g[k] = bgs[o]; }
        #pragma unroll 4
        for (int c2 = 0; c2 < 16; ++c2) {
            float4 wfp = *(float4*)&wfL[o][c2 * 4];
            float4 wgp = *(float4*)&wgL[o][c2 * 4];
            {
                int c = 2 * c2;
                float hv[9];
                *(float4*)&hv[0] = *(float4*)&hs[c][l0];
                *(float4*)&hv[4] = *(float4*)&hs[c][l0 + 4];
                hv[8] = hs[c][l0 + 8];
                #pragma unroll
                for (int k = 0; k < 8; ++k) {
                    f[k] += hv[k] * wfp.x + hv[k + 1] * wfp.y;
                    g[k] += hv[k] * wgp.x + hv[k + 1] * wgp.y;
                }
            }
            {
                int c = 2 * c2 + 1;
                float hv[9];
                *(float4*)&hv[0] = *(float4*)&hs[c][l0];
                *(float4*)&hv[4] = *(float4*)&hs[c][l0 + 4];
                hv[8] = hs[c][l0 + 8];
                #pragma unroll
                for (int k = 0; k < 8; ++k) {
                    f[k] += hv[k] * wfp.z + hv[k + 1] * wfp.w;
                    g[k] += hv[k] * wgp.z + hv[k + 1] * wgp.w;
                }
            }
        }
        us8 r8;
        float gv[8];
        #pragma unroll
        for (int k = 0; k < 8; ++k) {
            float ef = __expf(2.f * f[k]);
            float th = 1.f - 2.f / (ef + 1.f);         // tanh(f)
            float sg = 1.f / (1.f + __expf(-g[k]));    // sigmoid(g)
            gv[k] = th * sg;
            r8[k] = f2bits(gv[k]);
        }
        if (storeG)
            *(us8*)(G + ((size_t)(b * 32 + o) * 512 + n) * 64 + l0) = r8;
        #pragma unroll
        for (int k = 0; k < 8; ++k) gsT[l0 + k][o] = gv[k];
    }
    __syncthreads();

    // ---- skip phase: thread = (l = t>>2, o0 = (t&3)*8)
    {
        int l = t >> 2, o0 = (t & 3) * 8;
        if (l < LOUT_) {
            float s[8];
            #pragma unroll
            for (int oi = 0; oi < 8; ++oi) s[oi] = bss[o0 + oi];
            #pragma unroll 4
            for (int c = 0; c < 32; ++c) {
                float gvv = gsT[l + off][c];
                float4 w0 = *(float4*)&wskT[c][o0];
                float4 w1 = *(float4*)&wskT[c][o0 + 4];
                s[0] += gvv * w0.x; s[1] += gvv * w0.y; s[2] += gvv * w0.z; s[3] += gvv * w0.w;
                s[4] += gvv * w1.x; s[5] += gvv * w1.y; s[6] += gvv * w1.z; s[7] += gvv * w1.w;
            }
            float* po = out + ((size_t)(b * LOUT_ + l) * 512 + n) * 32 + o0;
            if (mode == 0) {
                *(float4*)po       = make_float4(s[0], s[1], s[2], s[3]);
                *(float4*)(po + 4) = make_float4(s[4], s[5], s[6], s[7]);
            } else {
                float4 a0 = *(float4*)po, a1 = *(float4*)(po + 4);
                float v[8] = {a0.x + s[0], a0.y + s[1], a0.z + s[2], a0.w + s[3],
                              a1.x + s[4], a1.y + s[5], a1.z + s[6], a1.w + s[7]};
                if (mode == 2) {
                    const float r = rsqrtf(1.f + 1e-5f);
                    #pragma unroll
                    for (int oi = 0; oi < 8; ++oi)
                        v[oi] = v[oi] * (og[o0 + oi] * r) + obb[o0 + oi];
                }
                *(float4*)po       = make_float4(v[0], v[1], v[2], v[3]);
                *(float4*)(po + 4) = make_float4(v[4], v[5], v[6], v[7]);
            }
        }
    }
}

// ---------------- K3: MFMA graph diffusion  Y[b,c,m,l] = sum_n adjT[m][n] * X[b,c,n,l]
__global__ void k_diffuse_mfma(const ushort_t* __restrict__ X,
                               const ushort_t* __restrict__ adjT,
                               ushort_t* __restrict__ Y) {
    __shared__ __align__(16) ushort_t lds[12288];  // As[64*64] + Xs[2*64*64]; Ys aliases
    ushort_t* As = lds;
    ushort_t* Xs = lds + 4096;
    int cp = blockIdx.x & 15;          // c-pair (2 channels)
    int mt = (blockIdx.x >> 4) & 7;
    int b  = blockIdx.x >> 7;
    int t  = threadIdx.x;
    int lane = t & 63, w = t >> 6;
    int c_loc = w & 1, lh = w >> 1;
    int m0 = mt * 64;
    int la = lane & 15, q = lane >> 4;
    const ushort_t* Xb = X + (size_t)(b * 32 + cp * 2) * 512 * 64;
    f32x4 acc[4][2];
    #pragma unroll
    for (int mi = 0; mi < 4; ++mi)
        #pragma unroll
        for (int li = 0; li < 2; ++li) acc[mi][li] = (f32x4)0.f;

    for (int n0 = 0; n0 < 512; n0 += 64) {
        __syncthreads();
        #pragma unroll
        for (int r = 0; r < 2; ++r) {              // stage As: adjT[m0..+63][n0..+63]
            int e = t + 256 * r;
            int ml = e >> 3, oct = e & 7;
            us8 v = *(const us8*)(adjT + (size_t)(m0 + ml) * 512 + n0 + oct * 8);
            *(us8*)(As + ml * 64 + (((oct + (ml >> 3)) & 7) << 3)) = v;
        }
        #pragma unroll
        for (int r = 0; r < 4; ++r) {              // stage Xs: [2][64 n][64 l]
            int e = t + 256 * r;
            int cl = e >> 9, nl = (e >> 3) & 63, oct = e & 7;
            us8 v = *(const us8*)(Xb + ((size_t)cl * 512 + n0 + nl) * 64 + oct * 8);
            *(us8*)(Xs + cl * 4096 + nl * 64 + (((oct + (nl >> 3)) & 7) << 3)) = v;
        }
        __syncthreads();
        #pragma unroll
        for (int ks = 0; ks < 2; ++ks) {           // two K=32 steps per chunk
            bf16x8 a[4];
            #pragma unroll
            for (int mi = 0; mi < 4; ++mi) {       // A[m=la][k=q*8+j]
                int m = mi * 16 + la;
                int bl = (ks * 4 + q + (m >> 3)) & 7;
                a[mi] = *(const bf16x8*)(As + m * 64 + bl * 8);
            }
            bf16x8 bb[2];
            #pragma unroll
            for (int li = 0; li < 2; ++li) {       // B[k=q*8+j][n=la]
                int l = lh * 32 + li * 16 + la;
                int rot = ((l >> 3) + ks * 4 + q) & 7;
                int col = rot * 8 + (l & 7);
                const ushort_t* p = Xs + c_loc * 4096 + (ks * 32 + q * 8) * 64 + col;
                bf16x8 v;
                #pragma unroll
                for (int j = 0; j < 8; ++j) v[j] = (short)p[j * 64];
                bb[li] = v;
            }
            #pragma unroll
            for (int mi = 0; mi < 4; ++mi)
                #pragma unroll
                for (int li = 0; li < 2; ++li)
                    acc[mi][li] = __builtin_amdgcn_mfma_f32_16x16x32_bf16(
                        a[mi], bb[li], acc[mi][li], 0, 0, 0);
        }
    }
    __syncthreads();
    ushort_t* Ys = lds;                            // [2][64][72]
    #pragma unroll
    for (int mi = 0; mi < 4; ++mi)
        #pragma unroll
        for (int li = 0; li < 2; ++li)
            #pragma unroll
            for (int r = 0; r < 4; ++r) {          // D: row=q*4+r, col=la
                int row = mi * 16 + q * 4 + r;
                int col = lh * 32 + li * 16 + la;
                Ys[c_loc * 4608 + row * 72 + col] = f2bits(acc[mi][li][r]);
            }
    __syncthreads();
    {
        int c = t >> 7, mrem = t & 127;
        int m = mrem >> 1, lq = mrem & 1;
        #pragma unroll
        for (int r = 0; r < 4; ++r) {
            int l0 = lq * 32 + r * 8;
            us8 v = *(const us8*)(Ys + c * 4608 + m * 72 + l0);
            *(us8*)(Y + ((size_t)(b * 32 + cp * 2 + c) * 512 + m0 + m) * 64 + l0) = v;
        }
    }
}

// ---------------- K4: graph-conv(96->32) + gcBN + residual + BN, in place over G.
// bf16 LDS staging: one aligned us8 read per K element. thread = (o, l-octet).
__global__ void k_gc3(ushort_t* __restrict__ G, const ushort_t* __restrict__ X1,
                      const ushort_t* __restrict__ X2, const ushort_t* __restrict__ hres,
                      const float* __restrict__ Wgc, const float* __restrict__ bgc,
                      const float* __restrict__ gg, const float* __restrict__ gb,
                      const float* __restrict__ bg2, const float* __restrict__ bb2) {
    __shared__ __align__(16) ushort_t cat[96][72];   // [G; X1; X2] rows, stride 144B
    __shared__ __align__(16) ushort_t hr[32][72];
    __shared__ float wc4[32][100];                   // row o: Wgc[o][0..95], quad-readable
    __shared__ float bsg[32];
    int b = blockIdx.x >> 9, n = blockIdx.x & 511, t = threadIdx.x;

    #pragma unroll
    for (int r = 0; r < 3; ++r) {                  // stage cat: 768 us8
        int e = t + 256 * r;
        int row = e >> 3, oct = (e & 7) * 8;
        const ushort_t* src = (row < 32) ? G : ((row < 64) ? X1 : X2);
        us8 v = *(const us8*)(src + ((size_t)(b * 32 + (row & 31)) * 512 + n) * 64 + oct);
        *(us8*)&cat[row][oct] = v;
    }
    {
        int row = t >> 3, oct = (t & 7) * 8;
        us8 v = *(const us8*)(hres + ((size_t)(b * 32 + row) * 512 + n) * 64 + oct);
        *(us8*)&hr[row][oct] = v;
    }
    #pragma unroll
    for (int r = 0; r < 3; ++r) {                  // stage weights: 768 float4
        int e4 = t + 256 * r;
        int o = e4 / 24, cq = e4 - o * 24;
        *(float4*)&wc4[o][cq * 4] = *(const float4*)(Wgc + e4 * 4);
    }
    if (t < 32) bsg[t] = bgc[t];
    __syncthreads();

    int o = t >> 3, l0 = (t & 7) * 8;
    float hv[9];
    {
        us8 v = *(const us8*)&hr[o][l0];
        #pragma unroll
        for (int k = 0; k < 8; ++k) hv[k] = bits2f(v[k]);
        hv[8] = bits2f(hr[o][l0 + 8]);
    }
    float s[8];
    #pragma unroll
    for (int k = 0; k < 8; ++k) s[k] = bsg[o];
    #pragma unroll 4
    for (int cq = 0; cq < 24; ++cq) {
        float4 w = *(float4*)&wc4[o][cq * 4];
        float wd[4] = {w.x, w.y, w.z, w.w};
        #pragma unroll
        for (int d = 0; d < 4; ++d) {
            us8 v = *(const us8*)&cat[cq * 4 + d][l0];
            float ww = wd[d];
            #pragma unroll
            for (int k = 0; k < 8; ++k) s[k] += bits2f(v[k]) * ww;
        }
    }
    const float r = rsqrtf(1.f + 1e-5f);
    float ga = gg[o] * r, gbv = gb[o], ba = bg2[o] * r, bbv = bb2[o];
    us8 outv;
    #pragma unroll
    for (int k = 0; k < 8; ++k) {
        float v = s[k] * ga + gbv + hv[k + 1];
        outv[k] = f2bits(v * ba + bbv);
    }
    *(us8*)(G + ((size_t)(b * 32 + o) * 512 + n) * 64 + l0) = outv;
}

extern "C" void kernel_launch(void* const* d_in, const int* in_sizes, int n_in,
                              void* d_out, int out_size, void* d_ws, size_t ws_size,
                              hipStream_t stream) {
    const float* x      = (const float*)d_in[0];
    const float* adj    = (const float*)d_in[1];
    const float* Wstart = (const float*)d_in[2];
    const float* bstart = (const float*)d_in[3];
    const float* Wf     = (const float*)d_in[4];
    const float* bf_    = (const float*)d_in[5];
    const float* Wg     = (const float*)d_in[6];
    const float* bg     = (const float*)d_in[7];
    const float* Wskip  = (const float*)d_in[8];
    const float* bskip  = (const float*)d_in[9];
    const float* Wgc    = (const float*)d_in[10];
    const float* bgc    = (const float*)d_in[11];
    const float* gcbn_g = (const float*)d_in[12];
    const float* gcbn_b = (const float*)d_in[13];
    const float* bn_g   = (const float*)d_in[14];
    const float* bn_b   = (const float*)d_in[15];
    const float* obn_g  = (const float*)d_in[16];
    const float* obn_b  = (const float*)d_in[17];
    float* out = (float*)d_out;

    // 4 bf16 scratch buffers (64 MiB) + adjT bf16 (512 KiB)
    ushort_t* P0   = (ushort_t*)d_ws;
    ushort_t* P1   = P0 + BUF_;
    ushort_t* P2   = P1 + BUF_;
    ushort_t* P3   = P2 + BUF_;
    ushort_t* adjT = P3 + BUF_;

    k_transA<<<64, 256, 0, stream>>>(adj, adjT);
    k_start<<<4096, 256, 0, stream>>>(x, Wstart, bstart, P0);

    ushort_t* h  = P0;
    ushort_t* Gb = P1;
    for (int i = 0; i < 3; ++i) {
        int Llen = L_ - i;       // valid input length this depth
        int mode = (i == 0) ? 0 : ((i == 2) ? 2 : 1);
        k_gs<<<B_ * N_, 256, 0, stream>>>(h, Wf + i * 2048, bf_ + i * 32,
                                          Wg + i * 2048, bg + i * 32,
                                          Wskip + i * 1024, bskip + i * 32,
                                          Gb, out, Llen, 2 - i, mode, (i < 2) ? 1 : 0,
                                          obn_g, obn_b);
        if (i == 2) break;
        k_diffuse_mfma<<<1024, 256, 0, stream>>>(Gb, adjT, P2);   // x1 = G . adj
        k_diffuse_mfma<<<1024, 256, 0, stream>>>(P2, adjT, P3);   // x2 = x1 . adj
        k_gc3<<<B_ * N_, 256, 0, stream>>>(Gb, P2, P3, h,
                                           Wgc + i * 3072, bgc + i * 32,
                                           gcbn_g + i * 32, gcbn_b + i * 32,
                                           bn_g + i * 32, bn_b + i * 32);
        ushort_t* tmp = h; h = Gb; Gb = tmp;   // new h lives where G was
    }
}

// Round 7
// 356.108 us; speedup vs baseline: 8.7886x; 1.4000x over previous
//
#include <hip/hip_runtime.h>
#include <hip/hip_bf16.h>

#define B_     8
#define CIN_   2
#define N_     512
#define C_     32
#define L_     64
#define LOUT_  61
#define BUF_   ((size_t)(8*32*512*64))   // 8,388,608 bf16 elements per scratch buffer

typedef __hip_bfloat16 bf16;
typedef unsigned short ushort_t;
typedef __attribute__((ext_vector_type(8))) unsigned short us8;
typedef __attribute__((ext_vector_type(8))) short bf16x8;
typedef __attribute__((ext_vector_type(4))) float f32x4;

static __device__ __forceinline__ float bits2f(ushort_t u) {
    return __uint_as_float(((unsigned)u) << 16);
}
static __device__ __forceinline__ ushort_t f2bits(float v) {   // RNE bf16 (finite inputs)
    unsigned u = __float_as_uint(v);
    return (ushort_t)((u + 0x7fffu + ((u >> 16) & 1u)) >> 16);
}

// ---------------- K0: start 1x1 conv (2->32 ch). One octet of l per thread.
__global__ void k_start(const float* __restrict__ x,
                        const float* __restrict__ Wst,
                        const float* __restrict__ bst,
                        ushort_t* __restrict__ h) {
    int idx = blockIdx.x * 256 + threadIdx.x;      // octet id, 1,048,576 total
    int l0 = (idx & 7) * 8;
    int n  = (idx >> 3) & 511;
    int o  = (idx >> 12) & 31;
    int b  = idx >> 17;
    float w0 = Wst[o * 2], w1 = Wst[o * 2 + 1], bb = bst[o];
    int xbase = (b * CIN_ * N_ + n) * L_ + l0;
    float va[8], vb[8];
    *(float4*)&va[0] = *(const float4*)(x + xbase);
    *(float4*)&va[4] = *(const float4*)(x + xbase + 4);
    *(float4*)&vb[0] = *(const float4*)(x + xbase + N_ * L_);
    *(float4*)&vb[4] = *(const float4*)(x + xbase + N_ * L_ + 4);
    us8 r;
    #pragma unroll
    for (int k = 0; k < 8; ++k) r[k] = f2bits(bb + va[k] * w0 + vb[k] * w1);
    *(us8*)(h + (size_t)idx * 8) = r;
}

// ---------------- K_T: adjT[m][n] = bf16(adj[n][m]), one-shot 512x512 transpose
__global__ void k_transA(const float* __restrict__ adj, ushort_t* __restrict__ adjT) {
    __shared__ float buf[64][65];
    int ti = blockIdx.x & 7;        // n-tile
    int tj = blockIdx.x >> 3;       // m-tile
    int t = threadIdx.x;
    for (int r = 0; r < 16; ++r) {
        int e = t + 256 * r;
        int rl = e >> 6, cl = e & 63;
        buf[rl][cl] = adj[(size_t)(ti * 64 + rl) * 512 + tj * 64 + cl];
    }
    __syncthreads();
    for (int r = 0; r < 16; ++r) {
        int e = t + 256 * r;
        int ml = e >> 6, nl = e & 63;
        adjT[(size_t)(tj * 64 + ml) * 512 + ti * 64 + nl] = f2bits(buf[nl][ml]);
    }
}

// ---------------- K_SQ: adj2T = adjT x adjT  (= (A^2)^T), bf16 MFMA, one-shot
__global__ __launch_bounds__(256, 2) void k_sq(const ushort_t* __restrict__ adjT,
                                               ushort_t* __restrict__ adj2T) {
    __shared__ __align__(16) ushort_t lds2[8192];   // As 4096 | Bs 4096; Ys aliases
    ushort_t* As = lds2;
    ushort_t* Bs = lds2 + 4096;
    int mt = blockIdx.x & 7, nc = blockIdx.x >> 3;
    int t = threadIdx.x, lane = t & 63, w = t >> 6;
    int la = lane & 15, q = lane >> 4;
    f32x4 acc[4];
    #pragma unroll
    for (int mi = 0; mi < 4; ++mi) acc[mi] = (f32x4)0.f;
    for (int p0 = 0; p0 < 512; p0 += 64) {
        __syncthreads();
        #pragma unroll
        for (int r = 0; r < 2; ++r) {
            int e = t + 256 * r, ml = e >> 3, oct = e & 7;
            int sw = ((oct + (ml >> 3)) & 7) << 3;
            *(us8*)(As + ml * 64 + sw) =
                *(const us8*)(adjT + (size_t)(mt * 64 + ml) * 512 + p0 + oct * 8);
            *(us8*)(Bs + ml * 64 + sw) =
                *(const us8*)(adjT + (size_t)(p0 + ml) * 512 + nc * 64 + oct * 8);
        }
        __syncthreads();
        #pragma unroll
        for (int ks = 0; ks < 2; ++ks) {
            bf16x8 a[4];
            #pragma unroll
            for (int mi = 0; mi < 4; ++mi) {
                int m = mi * 16 + la;
                int bl = (ks * 4 + q + (m >> 3)) & 7;
                a[mi] = *(const bf16x8*)(As + m * 64 + bl * 8);
            }
            bf16x8 bv;
            {
                int n = w * 16 + la;
                int rot = ((n >> 3) + ks * 4 + q) & 7;
                int col = rot * 8 + (n & 7);
                const ushort_t* p = Bs + (ks * 32 + q * 8) * 64 + col;
                #pragma unroll
                for (int j = 0; j < 8; ++j) bv[j] = (short)p[j * 64];
            }
            #pragma unroll
            for (int mi = 0; mi < 4; ++mi)
                acc[mi] = __builtin_amdgcn_mfma_f32_16x16x32_bf16(a[mi], bv, acc[mi], 0, 0, 0);
        }
    }
    __syncthreads();
    ushort_t* Ys = lds2;   // [64][72]
    #pragma unroll
    for (int mi = 0; mi < 4; ++mi)
        #pragma unroll
        for (int r = 0; r < 4; ++r)
            Ys[(mi * 16 + q * 4 + r) * 72 + w * 16 + la] = f2bits(acc[mi][r]);
    __syncthreads();
    #pragma unroll
    for (int r = 0; r < 2; ++r) {
        int e = t + 256 * r, ml = e >> 3, oct = e & 7;
        us8 v = *(const us8*)(Ys + ml * 72 + oct * 8);
        *(us8*)(adj2T + (size_t)(mt * 64 + ml) * 512 + nc * 64 + oct * 8) = v;
    }
}

// ---------------- K1: FUSED MFMA gated conv + skip conv (+ optional output BN)
// Block: (b, 4-node chunk). Wave w owns node row nr=w (64 l cols = 4 col-tiles).
// Conv GEMM: [32o x 64k] x [64k x cols], k=(c,tap); tap1 reads LDS at l+1.
// Skip GEMM: [32o x 32c] x G (in LDS, rows disjoint per wave -> no barrier).
__global__ __launch_bounds__(256, 2) void k_gs_mfma(
        const ushort_t* __restrict__ h,
        const float* __restrict__ Wf, const float* __restrict__ bfp,
        const float* __restrict__ Wg, const float* __restrict__ bgp,
        const float* __restrict__ Wsk, const float* __restrict__ bsk,
        ushort_t* __restrict__ G, float* __restrict__ out,
        int off, int mode, int storeG,
        const float* __restrict__ og, const float* __restrict__ obb) {
    __shared__ __align__(16) ushort_t Hs[128 * 72];   // H-tile -> G-tile -> St(float[128][36])
    __shared__ __align__(16) ushort_t Asf[32 * 72];
    __shared__ __align__(16) ushort_t Asg[32 * 72];
    __shared__ __align__(16) ushort_t As2[32 * 40];
    __shared__ float bfv[32], bgv[32], bsv[32];
    int t = threadIdx.x;
    int b = blockIdx.x >> 7, n0 = (blockIdx.x & 127) * 4;
    int lane = t & 63, w = t >> 6;
    int la = lane & 15, q = lane >> 4;

    // stage weight A-matrices (fp32 global -> bf16 LDS, contiguous [o][k] rows)
    {
        int o = t >> 3, k8 = (t & 7) * 8;
        us8 vf, vg;
        #pragma unroll
        for (int i = 0; i < 8; ++i) {
            int k = k8 + i, c = k & 31, tap = k >> 5;
            vf[i] = f2bits(Wf[o * 64 + c * 2 + tap]);
            vg[i] = f2bits(Wg[o * 64 + c * 2 + tap]);
        }
        *(us8*)(Asf + o * 72 + k8) = vf;
        *(us8*)(Asg + o * 72 + k8) = vg;
        if (k8 < 32) {
            us8 vs;
            #pragma unroll
            for (int i = 0; i < 8; ++i) vs[i] = f2bits(Wsk[o * 32 + k8 + i]);
            *(us8*)(As2 + o * 40 + k8) = vs;
        }
        if (t < 32) { bfv[t] = bfp[t]; bgv[t] = bgp[t]; bsv[t] = bsk[t]; }
    }
    // stage H tile: row = c*4+nr, 16B-block swizzle; zero pad cols 64..71
    const ushort_t* hb = h + (size_t)(b * 32) * 512 * 64;
    #pragma unroll
    for (int r = 0; r < 4; ++r) {
        int e = t + 256 * r;
        int row = e >> 3, oct = e & 7;
        us8 v = *(const us8*)(hb + ((size_t)(row >> 2) * 512 + n0 + (row & 3)) * 64 + oct * 8);
        int sw = (oct + row + (row >> 5)) & 7;
        *(us8*)(Hs + row * 72 + sw * 8) = v;
    }
    {
        int row = t >> 1, hf = t & 1;
        *(uint2*)(Hs + row * 72 + 64 + hf * 4) = make_uint2(0u, 0u);
    }
    __syncthreads();

    // A-frag preload
    bf16x8 af[2][2], ag[2][2];
    #pragma unroll
    for (int mt = 0; mt < 2; ++mt)
        #pragma unroll
        for (int ks = 0; ks < 2; ++ks) {
            af[mt][ks] = *(const bf16x8*)(Asf + (mt * 16 + la) * 72 + ks * 32 + q * 8);
            ag[mt][ks] = *(const bf16x8*)(Asg + (mt * 16 + la) * 72 + ks * 32 + q * 8);
        }

    // conv MFMA
    f32x4 fa[2][4], ga[2][4];
    #pragma unroll
    for (int mt = 0; mt < 2; ++mt)
        #pragma unroll
        for (int ct = 0; ct < 4; ++ct) { fa[mt][ct] = (f32x4)0.f; ga[mt][ct] = (f32x4)0.f; }
    #pragma unroll
    for (int ct = 0; ct < 4; ++ct) {
        #pragma unroll
        for (int ks = 0; ks < 2; ++ks) {
            int le = ct * 16 + la + ks;
            bf16x8 bv;
            #pragma unroll
            for (int j = 0; j < 8; ++j) {
                int row = 32 * q + 4 * j + w;
                int pos = (le < 64) ? ((((le >> 3) + row + q) & 7) * 8 + (le & 7)) : le;
                bv[j] = (short)Hs[row * 72 + pos];
            }
            #pragma unroll
            for (int mt = 0; mt < 2; ++mt) {
                fa[mt][ct] = __builtin_amdgcn_mfma_f32_16x16x32_bf16(af[mt][ks], bv, fa[mt][ct], 0, 0, 0);
                ga[mt][ct] = __builtin_amdgcn_mfma_f32_16x16x32_bf16(ag[mt][ks], bv, ga[mt][ct], 0, 0, 0);
            }
        }
    }

    // activation + write G tile into Hs region (rows o*4+w: disjoint per wave)
    #pragma unroll
    for (int mt = 0; mt < 2; ++mt)
        #pragma unroll
        for (int ct = 0; ct < 4; ++ct)
            #pragma unroll
            for (int r = 0; r < 4; ++r) {
                int o = mt * 16 + q * 4 + r;
                float fv = fa[mt][ct][r] + bfv[o];
                float gv = ga[mt][ct][r] + bgv[o];
                float ef = __expf(2.f * fv);
                float act = (1.f - 2.f / (ef + 1.f)) * (1.f / (1.f + __expf(-gv)));
                int l = ct * 16 + la;
                int row = o * 4 + w;
                int sw = ((l >> 3) + row + (row >> 5)) & 7;
                Hs[row * 72 + sw * 8 + (l & 7)] = f2bits(act);
            }

    // skip MFMA (reads own wave's rows of G tile; same-wave LDS dep only)
    bf16x8 a2[2];
    a2[0] = *(const bf16x8*)(As2 + la * 40 + q * 8);
    a2[1] = *(const bf16x8*)(As2 + (16 + la) * 40 + q * 8);
    f32x4 sa[2][4];
    #pragma unroll
    for (int mt = 0; mt < 2; ++mt)
        #pragma unroll
        for (int ct = 0; ct < 4; ++ct) sa[mt][ct] = (f32x4)0.f;
    #pragma unroll
    for (int ct = 0; ct < 4; ++ct) {
        int le = ct * 16 + la + off;
        bf16x8 bv;
        #pragma unroll
        for (int j = 0; j < 8; ++j) {
            int row = 32 * q + 4 * j + w;
            int pos = (le < 64) ? ((((le >> 3) + row + q) & 7) * 8 + (le & 7)) : le;
            bv[j] = (short)Hs[row * 72 + pos];
        }
        sa[0][ct] = __builtin_amdgcn_mfma_f32_16x16x32_bf16(a2[0], bv, sa[0][ct], 0, 0, 0);
        sa[1][ct] = __builtin_amdgcn_mfma_f32_16x16x32_bf16(a2[1], bv, sa[1][ct], 0, 0, 0);
    }
    __syncthreads();

    // G global store (reads all rows)
    if (storeG) {
        #pragma unroll
        for (int r = 0; r < 4; ++r) {
            int e = t + 256 * r;
            int row = e >> 3, oct = e & 7;
            int sw = (oct + row + (row >> 5)) & 7;
            us8 v = *(const us8*)(Hs + row * 72 + sw * 8);
            *(us8*)(G + ((size_t)(b * 32 + (row >> 2)) * 512 + n0 + (row & 3)) * 64 + oct * 8) = v;
        }
    }
    __syncthreads();

    // skip output via LDS transpose, two half-passes (St = float[128][36] reuses Hs)
    float* St = (float*)Hs;
    const float rbn = rsqrtf(1.f + 1e-5f);
    #pragma unroll
    for (int half = 0; half < 2; ++half) {
        if ((w >> 1) == half) {
            #pragma unroll
            for (int mt = 0; mt < 2; ++mt)
                #pragma unroll
                for (int ct = 0; ct < 4; ++ct) {
                    int col = (w & 1) * 64 + ct * 16 + la;
                    int ob = mt * 16 + q * 4;
                    float4 sv = make_float4(sa[mt][ct][0] + bsv[ob],
                                            sa[mt][ct][1] + bsv[ob + 1],
                                            sa[mt][ct][2] + bsv[ob + 2],
                                            sa[mt][ct][3] + bsv[ob + 3]);
                    *(float4*)(St + col * 36 + ob) = sv;
                }
        }
        __syncthreads();
        {
            int col = t >> 1, o0 = (t & 1) * 16;
            int nr = half * 2 + (col >> 6), l = col & 63;
            if (l < LOUT_) {
                float* po = out + ((size_t)(b * LOUT_ + l) * 512 + n0 + nr) * 32 + o0;
                #pragma unroll
                for (int i = 0; i < 4; ++i) {
                    float4 s = *(float4*)(St + col * 36 + o0 + i * 4);
                    if (mode == 0) {
                        *(float4*)(po + i * 4) = s;
                    } else {
                        float4 old = *(float4*)(po + i * 4);
                        float4 vv = make_float4(old.x + s.x, old.y + s.y,
                                                old.z + s.z, old.w + s.w);
                        if (mode == 2) {
                            int ob = o0 + i * 4;
                            vv.x = vv.x * (og[ob] * rbn) + obb[ob];
                            vv.y = vv.y * (og[ob + 1] * rbn) + obb[ob + 1];
                            vv.z = vv.z * (og[ob + 2] * rbn) + obb[ob + 2];
                            vv.w = vv.w * (og[ob + 3] * rbn) + obb[ob + 3];
                        }
                        *(float4*)(po + i * 4) = vv;
                    }
                }
            }
        }
        __syncthreads();
    }
}

// ---------------- K3: dual MFMA diffusion: x1 = G.adj, x2 = G.adj2 in one pass
__global__ __launch_bounds__(256, 2) void k_diffuse2(
        const ushort_t* __restrict__ X, const ushort_t* __restrict__ adjT,
        const ushort_t* __restrict__ adj2T,
        ushort_t* __restrict__ Y1, ushort_t* __restrict__ Y2) {
    __shared__ __align__(16) ushort_t lds[16384];  // As1|As2|Xs; Ys aliases
    ushort_t* As1 = lds;
    ushort_t* As2 = lds + 4096;
    ushort_t* Xs  = lds + 8192;
    int cp = blockIdx.x & 15;          // c-pair (2 channels)
    int mt = (blockIdx.x >> 4) & 7;
    int b  = blockIdx.x >> 7;
    int t  = threadIdx.x;
    int lane = t & 63, w = t >> 6;
    int c_loc = w & 1, lh = w >> 1;
    int m0 = mt * 64;
    int la = lane & 15, q = lane >> 4;
    const ushort_t* Xb = X + (size_t)(b * 32 + cp * 2) * 512 * 64;
    f32x4 acc1[4][2], acc2[4][2];
    #pragma unroll
    for (int mi = 0; mi < 4; ++mi)
        #pragma unroll
        for (int li = 0; li < 2; ++li) { acc1[mi][li] = (f32x4)0.f; acc2[mi][li] = (f32x4)0.f; }

    for (int n0 = 0; n0 < 512; n0 += 64) {
        __syncthreads();
        #pragma unroll
        for (int r = 0; r < 2; ++r) {
            int e = t + 256 * r;
            int ml = e >> 3, oct = e & 7;
            int sw = ((oct + (ml >> 3)) & 7) << 3;
            *(us8*)(As1 + ml * 64 + sw) =
                *(const us8*)(adjT + (size_t)(m0 + ml) * 512 + n0 + oct * 8);
            *(us8*)(As2 + ml * 64 + sw) =
                *(const us8*)(adj2T + (size_t)(m0 + ml) * 512 + n0 + oct * 8);
        }
        #pragma unroll
        for (int r = 0; r < 4; ++r) {
            int e = t + 256 * r;
            int cl = e >> 9, nl = (e >> 3) & 63, oct = e & 7;
            us8 v = *(const us8*)(Xb + ((size_t)cl * 512 + n0 + nl) * 64 + oct * 8);
            *(us8*)(Xs + cl * 4096 + nl * 64 + (((oct + (nl >> 3)) & 7) << 3)) = v;
        }
        __syncthreads();
        #pragma unroll
        for (int ks = 0; ks < 2; ++ks) {
            bf16x8 a1[4], a2v[4];
            #pragma unroll
            for (int mi = 0; mi < 4; ++mi) {
                int m = mi * 16 + la;
                int bl = (ks * 4 + q + (m >> 3)) & 7;
                a1[mi]  = *(const bf16x8*)(As1 + m * 64 + bl * 8);
                a2v[mi] = *(const bf16x8*)(As2 + m * 64 + bl * 8);
            }
            bf16x8 bb[2];
            #pragma unroll
            for (int li = 0; li < 2; ++li) {
                int l = lh * 32 + li * 16 + la;
                int rot = ((l >> 3) + ks * 4 + q) & 7;
                int col = rot * 8 + (l & 7);
                const ushort_t* p = Xs + c_loc * 4096 + (ks * 32 + q * 8) * 64 + col;
                bf16x8 v;
                #pragma unroll
                for (int j = 0; j < 8; ++j) v[j] = (short)p[j * 64];
                bb[li] = v;
            }
            #pragma unroll
            for (int mi = 0; mi < 4; ++mi)
                #pragma unroll
                for (int li = 0; li < 2; ++li) {
                    acc1[mi][li] = __builtin_amdgcn_mfma_f32_16x16x32_bf16(a1[mi], bb[li], acc1[mi][li], 0, 0, 0);
                    acc2[mi][li] = __builtin_amdgcn_mfma_f32_16x16x32_bf16(a2v[mi], bb[li], acc2[mi][li], 0, 0, 0);
                }
        }
    }
    ushort_t* Ys = lds;                            // [2][64][72]
    #pragma unroll
    for (int pass = 0; pass < 2; ++pass) {
        __syncthreads();
        f32x4 (*src)[2] = pass ? acc2 : acc1;
        #pragma unroll
        for (int mi = 0; mi < 4; ++mi)
            #pragma unroll
            for (int li = 0; li < 2; ++li)
                #pragma unroll
                for (int r = 0; r < 4; ++r) {
                    int row = mi * 16 + q * 4 + r;
                    int col = lh * 32 + li * 16 + la;
                    Ys[c_loc * 4608 + row * 72 + col] = f2bits(src[mi][li][r]);
                }
        __syncthreads();
        ushort_t* Yo = pass ? Y2 : Y1;
        int c = t >> 7, mrem = t & 127;
        int m = mrem >> 1, lq = mrem & 1;
        #pragma unroll
        for (int r = 0; r < 4; ++r) {
            int l0 = lq * 32 + r * 8;
            us8 v = *(const us8*)(Ys + c * 4608 + m * 72 + l0);
            *(us8*)(Yo + ((size_t)(b * 32 + cp * 2 + c) * 512 + m0 + m) * 64 + l0) = v;
        }
    }
}

// ---------------- K4: graph-conv(96->32) + gcBN + residual + BN, in place over G.
__global__ void k_gc3(ushort_t* __restrict__ G, const ushort_t* __restrict__ X1,
                      const ushort_t* __restrict__ X2, const ushort_t* __restrict__ hres,
                      const float* __restrict__ Wgc, const float* __restrict__ bgc,
                      const float* __restrict__ gg, const float* __restrict__ gb,
                      const float* __restrict__ bg2, const float* __restrict__ bb2) {
    __shared__ __align__(16) ushort_t cat[96][72];   // [G; X1; X2] rows
    __shared__ __align__(16) ushort_t hr[32][72];
    __shared__ float wc4[32][100];                   // row o: Wgc[o][0..95]
    __shared__ float bsg[32];
    int b = blockIdx.x >> 9, n = blockIdx.x & 511, t = threadIdx.x;

    #pragma unroll
    for (int r = 0; r < 3; ++r) {
        int e = t + 256 * r;
        int row = e >> 3, oct = (e & 7) * 8;
        const ushort_t* src = (row < 32) ? G : ((row < 64) ? X1 : X2);
        us8 v = *(const us8*)(src + ((size_t)(b * 32 + (row & 31)) * 512 + n) * 64 + oct);
        *(us8*)&cat[row][oct] = v;
    }
    {
        int row = t >> 3, oct = (t & 7) * 8;
        us8 v = *(const us8*)(hres + ((size_t)(b * 32 + row) * 512 + n) * 64 + oct);
        *(us8*)&hr[row][oct] = v;
    }
    #pragma unroll
    for (int r = 0; r < 3; ++r) {
        int e4 = t + 256 * r;
        int o = e4 / 24, cq = e4 - o * 24;
        *(float4*)&wc4[o][cq * 4] = *(const float4*)(Wgc + e4 * 4);
    }
    if (t < 32) bsg[t] = bgc[t];
    __syncthreads();

    int o = t >> 3, l0 = (t & 7) * 8;
    float hv[9];
    {
        us8 v = *(const us8*)&hr[o][l0];
        #pragma unroll
        for (int k = 0; k < 8; ++k) hv[k] = bits2f(v[k]);
        hv[8] = bits2f(hr[o][l0 + 8]);
    }
    float s[8];
    #pragma unroll
    for (int k = 0; k < 8; ++k) s[k] = bsg[o];
    #pragma unroll 4
    for (int cq = 0; cq < 24; ++cq) {
        float4 wv = *(float4*)&wc4[o][cq * 4];
        float wd[4] = {wv.x, wv.y, wv.z, wv.w};
        #pragma unroll
        for (int d = 0; d < 4; ++d) {
            us8 v = *(const us8*)&cat[cq * 4 + d][l0];
            float ww = wd[d];
            #pragma unroll
            for (int k = 0; k < 8; ++k) s[k] += bits2f(v[k]) * ww;
        }
    }
    const float r = rsqrtf(1.f + 1e-5f);
    float ga = gg[o] * r, gbv = gb[o], ba = bg2[o] * r, bbv = bb2[o];
    us8 outv;
    #pragma unroll
    for (int k = 0; k < 8; ++k) {
        float v = s[k] * ga + gbv + hv[k + 1];
        outv[k] = f2bits(v * ba + bbv);
    }
    *(us8*)(G + ((size_t)(b * 32 + o) * 512 + n) * 64 + l0) = outv;
}

extern "C" void kernel_launch(void* const* d_in, const int* in_sizes, int n_in,
                              void* d_out, int out_size, void* d_ws, size_t ws_size,
                              hipStream_t stream) {
    const float* x      = (const float*)d_in[0];
    const float* adj    = (const float*)d_in[1];
    const float* Wstart = (const float*)d_in[2];
    const float* bstart = (const float*)d_in[3];
    const float* Wf     = (const float*)d_in[4];
    const float* bf_    = (const float*)d_in[5];
    const float* Wg     = (const float*)d_in[6];
    const float* bg     = (const float*)d_in[7];
    const float* Wskip  = (const float*)d_in[8];
    const float* bskip  = (const float*)d_in[9];
    const float* Wgc    = (const float*)d_in[10];
    const float* bgc    = (const float*)d_in[11];
    const float* gcbn_g = (const float*)d_in[12];
    const float* gcbn_b = (const float*)d_in[13];
    const float* bn_g   = (const float*)d_in[14];
    const float* bn_b   = (const float*)d_in[15];
    const float* obn_g  = (const float*)d_in[16];
    const float* obn_b  = (const float*)d_in[17];
    float* out = (float*)d_out;

    // 4 bf16 scratch buffers (64 MiB) + adjT + adj2T (512 KiB each)
    ushort_t* P0    = (ushort_t*)d_ws;
    ushort_t* P1    = P0 + BUF_;
    ushort_t* P2    = P1 + BUF_;
    ushort_t* P3    = P2 + BUF_;
    ushort_t* adjT  = P3 + BUF_;
    ushort_t* adj2T = adjT + 512 * 512;

    k_transA<<<64, 256, 0, stream>>>(adj, adjT);
    k_sq<<<64, 256, 0, stream>>>(adjT, adj2T);
    k_start<<<4096, 256, 0, stream>>>(x, Wstart, bstart, P0);

    ushort_t* h  = P0;
    ushort_t* Gb = P1;
    for (int i = 0; i < 3; ++i) {
        int mode = (i == 0) ? 0 : ((i == 2) ? 2 : 1);
        k_gs_mfma<<<1024, 256, 0, stream>>>(h, Wf + i * 2048, bf_ + i * 32,
                                            Wg + i * 2048, bg + i * 32,
                                            Wskip + i * 1024, bskip + i * 32,
                                            Gb, out, 2 - i, mode, (i < 2) ? 1 : 0,
                                            obn_g, obn_b);
        if (i == 2) break;
        k_diffuse2<<<1024, 256, 0, stream>>>(Gb, adjT, adj2T, P2, P3);  // x1, x2
        k_gc3<<<B_ * N_, 256, 0, stream>>>(Gb, P2, P3, h,
                                           Wgc + i * 3072, bgc + i * 32,
                                           gcbn_g + i * 32, gcbn_b + i * 32,
                                           bn_g + i * 32, bn_b + i * 32);
        ushort_t* tmp = h; h = Gb; Gb = tmp;   // new h lives where G was
    }
}

// Round 8
// 317.770 us; speedup vs baseline: 9.8489x; 1.1206x over previous
//
#include <hip/hip_runtime.h>
#include <hip/hip_bf16.h>

#define B_     8
#define CIN_   2
#define N_     512
#define C_     32
#define L_     64
#define LOUT_  61
#define BUF_   ((size_t)(8*32*512*64))   // 8,388,608 bf16 elements per scratch buffer

typedef __hip_bfloat16 bf16;
typedef unsigned short ushort_t;
typedef __attribute__((ext_vector_type(8))) unsigned short us8;
typedef __attribute__((ext_vector_type(8))) short bf16x8;
typedef __attribute__((ext_vector_type(4))) float f32x4;

static __device__ __forceinline__ float bits2f(ushort_t u) {
    return __uint_as_float(((unsigned)u) << 16);
}
static __device__ __forceinline__ ushort_t f2bits(float v) {   // RNE bf16 (finite inputs)
    unsigned u = __float_as_uint(v);
    return (ushort_t)((u + 0x7fffu + ((u >> 16) & 1u)) >> 16);
}

// ---------------- K0: start 1x1 conv (2->32 ch). One octet of l per thread.
__global__ void k_start(const float* __restrict__ x,
                        const float* __restrict__ Wst,
                        const float* __restrict__ bst,
                        ushort_t* __restrict__ h) {
    int idx = blockIdx.x * 256 + threadIdx.x;      // octet id, 1,048,576 total
    int l0 = (idx & 7) * 8;
    int n  = (idx >> 3) & 511;
    int o  = (idx >> 12) & 31;
    int b  = idx >> 17;
    float w0 = Wst[o * 2], w1 = Wst[o * 2 + 1], bb = bst[o];
    int xbase = (b * CIN_ * N_ + n) * L_ + l0;
    float va[8], vb[8];
    *(float4*)&va[0] = *(const float4*)(x + xbase);
    *(float4*)&va[4] = *(const float4*)(x + xbase + 4);
    *(float4*)&vb[0] = *(const float4*)(x + xbase + N_ * L_);
    *(float4*)&vb[4] = *(const float4*)(x + xbase + N_ * L_ + 4);
    us8 r;
    #pragma unroll
    for (int k = 0; k < 8; ++k) r[k] = f2bits(bb + va[k] * w0 + vb[k] * w1);
    *(us8*)(h + (size_t)idx * 8) = r;
}

// ---------------- K_T: adjT[m][n] = bf16(adj[n][m]), one-shot 512x512 transpose
__global__ void k_transA(const float* __restrict__ adj, ushort_t* __restrict__ adjT) {
    __shared__ float buf[64][65];
    int ti = blockIdx.x & 7;        // n-tile
    int tj = blockIdx.x >> 3;       // m-tile
    int t = threadIdx.x;
    for (int r = 0; r < 16; ++r) {
        int e = t + 256 * r;
        int rl = e >> 6, cl = e & 63;
        buf[rl][cl] = adj[(size_t)(ti * 64 + rl) * 512 + tj * 64 + cl];
    }
    __syncthreads();
    for (int r = 0; r < 16; ++r) {
        int e = t + 256 * r;
        int ml = e >> 6, nl = e & 63;
        adjT[(size_t)(tj * 64 + ml) * 512 + ti * 64 + nl] = f2bits(buf[nl][ml]);
    }
}

// ---------------- K_SQ: adj2T = adjT x adjT  (= (A^2)^T), bf16 MFMA, one-shot
__global__ __launch_bounds__(256, 2) void k_sq(const ushort_t* __restrict__ adjT,
                                               ushort_t* __restrict__ adj2T) {
    __shared__ __align__(16) ushort_t lds2[8192];   // As 4096 | Bs 4096; Ys aliases
    ushort_t* As = lds2;
    ushort_t* Bs = lds2 + 4096;
    int mt = blockIdx.x & 7, nc = blockIdx.x >> 3;
    int t = threadIdx.x, lane = t & 63, w = t >> 6;
    int la = lane & 15, q = lane >> 4;
    f32x4 acc[4];
    #pragma unroll
    for (int mi = 0; mi < 4; ++mi) acc[mi] = (f32x4)0.f;
    for (int p0 = 0; p0 < 512; p0 += 64) {
        __syncthreads();
        #pragma unroll
        for (int r = 0; r < 2; ++r) {
            int e = t + 256 * r, ml = e >> 3, oct = e & 7;
            int sw = ((oct + (ml >> 3)) & 7) << 3;
            *(us8*)(As + ml * 64 + sw) =
                *(const us8*)(adjT + (size_t)(mt * 64 + ml) * 512 + p0 + oct * 8);
            *(us8*)(Bs + ml * 64 + sw) =
                *(const us8*)(adjT + (size_t)(p0 + ml) * 512 + nc * 64 + oct * 8);
        }
        __syncthreads();
        #pragma unroll
        for (int ks = 0; ks < 2; ++ks) {
            bf16x8 a[4];
            #pragma unroll
            for (int mi = 0; mi < 4; ++mi) {
                int m = mi * 16 + la;
                int bl = (ks * 4 + q + (m >> 3)) & 7;
                a[mi] = *(const bf16x8*)(As + m * 64 + bl * 8);
            }
            bf16x8 bv;
            {
                int n = w * 16 + la;
                int rot = ((n >> 3) + ks * 4 + q) & 7;
                int col = rot * 8 + (n & 7);
                const ushort_t* p = Bs + (ks * 32 + q * 8) * 64 + col;
                #pragma unroll
                for (int j = 0; j < 8; ++j) bv[j] = (short)p[j * 64];
            }
            #pragma unroll
            for (int mi = 0; mi < 4; ++mi)
                acc[mi] = __builtin_amdgcn_mfma_f32_16x16x32_bf16(a[mi], bv, acc[mi], 0, 0, 0);
        }
    }
    __syncthreads();
    ushort_t* Ys = lds2;   // [64][72]
    #pragma unroll
    for (int mi = 0; mi < 4; ++mi)
        #pragma unroll
        for (int r = 0; r < 4; ++r)
            Ys[(mi * 16 + q * 4 + r) * 72 + w * 16 + la] = f2bits(acc[mi][r]);
    __syncthreads();
    #pragma unroll
    for (int r = 0; r < 2; ++r) {
        int e = t + 256 * r, ml = e >> 3, oct = e & 7;
        us8 v = *(const us8*)(Ys + ml * 72 + oct * 8);
        *(us8*)(adj2T + (size_t)(mt * 64 + ml) * 512 + nc * 64 + oct * 8) = v;
    }
}

// ---------------- K1: FUSED MFMA gated conv + skip conv (+ optional output BN)
__global__ __launch_bounds__(256, 2) void k_gs_mfma(
        const ushort_t* __restrict__ h,
        const float* __restrict__ Wf, const float* __restrict__ bfp,
        const float* __restrict__ Wg, const float* __restrict__ bgp,
        const float* __restrict__ Wsk, const float* __restrict__ bsk,
        ushort_t* __restrict__ G, float* __restrict__ out,
        int off, int mode, int storeG,
        const float* __restrict__ og, const float* __restrict__ obb) {
    __shared__ __align__(16) ushort_t Hs[128 * 72];   // H-tile -> G-tile -> St(float[128][36])
    __shared__ __align__(16) ushort_t Asf[32 * 72];
    __shared__ __align__(16) ushort_t Asg[32 * 72];
    __shared__ __align__(16) ushort_t As2[32 * 40];
    __shared__ float bfv[32], bgv[32], bsv[32];
    int t = threadIdx.x;
    int b = blockIdx.x >> 7, n0 = (blockIdx.x & 127) * 4;
    int lane = t & 63, w = t >> 6;
    int la = lane & 15, q = lane >> 4;

    {
        int o = t >> 3, k8 = (t & 7) * 8;
        us8 vf, vg;
        #pragma unroll
        for (int i = 0; i < 8; ++i) {
            int k = k8 + i, c = k & 31, tap = k >> 5;
            vf[i] = f2bits(Wf[o * 64 + c * 2 + tap]);
            vg[i] = f2bits(Wg[o * 64 + c * 2 + tap]);
        }
        *(us8*)(Asf + o * 72 + k8) = vf;
        *(us8*)(Asg + o * 72 + k8) = vg;
        if (k8 < 32) {
            us8 vs;
            #pragma unroll
            for (int i = 0; i < 8; ++i) vs[i] = f2bits(Wsk[o * 32 + k8 + i]);
            *(us8*)(As2 + o * 40 + k8) = vs;
        }
        if (t < 32) { bfv[t] = bfp[t]; bgv[t] = bgp[t]; bsv[t] = bsk[t]; }
    }
    const ushort_t* hb = h + (size_t)(b * 32) * 512 * 64;
    #pragma unroll
    for (int r = 0; r < 4; ++r) {
        int e = t + 256 * r;
        int row = e >> 3, oct = e & 7;
        us8 v = *(const us8*)(hb + ((size_t)(row >> 2) * 512 + n0 + (row & 3)) * 64 + oct * 8);
        int sw = (oct + row + (row >> 5)) & 7;
        *(us8*)(Hs + row * 72 + sw * 8) = v;
    }
    {
        int row = t >> 1, hf = t & 1;
        *(uint2*)(Hs + row * 72 + 64 + hf * 4) = make_uint2(0u, 0u);
    }
    __syncthreads();

    bf16x8 af[2][2], ag[2][2];
    #pragma unroll
    for (int mt = 0; mt < 2; ++mt)
        #pragma unroll
        for (int ks = 0; ks < 2; ++ks) {
            af[mt][ks] = *(const bf16x8*)(Asf + (mt * 16 + la) * 72 + ks * 32 + q * 8);
            ag[mt][ks] = *(const bf16x8*)(Asg + (mt * 16 + la) * 72 + ks * 32 + q * 8);
        }

    f32x4 fa[2][4], ga[2][4];
    #pragma unroll
    for (int mt = 0; mt < 2; ++mt)
        #pragma unroll
        for (int ct = 0; ct < 4; ++ct) { fa[mt][ct] = (f32x4)0.f; ga[mt][ct] = (f32x4)0.f; }
    #pragma unroll
    for (int ct = 0; ct < 4; ++ct) {
        #pragma unroll
        for (int ks = 0; ks < 2; ++ks) {
            int le = ct * 16 + la + ks;
            bf16x8 bv;
            #pragma unroll
            for (int j = 0; j < 8; ++j) {
                int row = 32 * q + 4 * j + w;
                int pos = (le < 64) ? ((((le >> 3) + row + q) & 7) * 8 + (le & 7)) : le;
                bv[j] = (short)Hs[row * 72 + pos];
            }
            #pragma unroll
            for (int mt = 0; mt < 2; ++mt) {
                fa[mt][ct] = __builtin_amdgcn_mfma_f32_16x16x32_bf16(af[mt][ks], bv, fa[mt][ct], 0, 0, 0);
                ga[mt][ct] = __builtin_amdgcn_mfma_f32_16x16x32_bf16(ag[mt][ks], bv, ga[mt][ct], 0, 0, 0);
            }
        }
    }

    #pragma unroll
    for (int mt = 0; mt < 2; ++mt)
        #pragma unroll
        for (int ct = 0; ct < 4; ++ct)
            #pragma unroll
            for (int r = 0; r < 4; ++r) {
                int o = mt * 16 + q * 4 + r;
                float fv = fa[mt][ct][r] + bfv[o];
                float gv = ga[mt][ct][r] + bgv[o];
                float ef = __expf(2.f * fv);
                float act = (1.f - 2.f / (ef + 1.f)) * (1.f / (1.f + __expf(-gv)));
                int l = ct * 16 + la;
                int row = o * 4 + w;
                int sw = ((l >> 3) + row + (row >> 5)) & 7;
                Hs[row * 72 + sw * 8 + (l & 7)] = f2bits(act);
            }

    bf16x8 a2[2];
    a2[0] = *(const bf16x8*)(As2 + la * 40 + q * 8);
    a2[1] = *(const bf16x8*)(As2 + (16 + la) * 40 + q * 8);
    f32x4 sa[2][4];
    #pragma unroll
    for (int mt = 0; mt < 2; ++mt)
        #pragma unroll
        for (int ct = 0; ct < 4; ++ct) sa[mt][ct] = (f32x4)0.f;
    #pragma unroll
    for (int ct = 0; ct < 4; ++ct) {
        int le = ct * 16 + la + off;
        bf16x8 bv;
        #pragma unroll
        for (int j = 0; j < 8; ++j) {
            int row = 32 * q + 4 * j + w;
            int pos = (le < 64) ? ((((le >> 3) + row + q) & 7) * 8 + (le & 7)) : le;
            bv[j] = (short)Hs[row * 72 + pos];
        }
        sa[0][ct] = __builtin_amdgcn_mfma_f32_16x16x32_bf16(a2[0], bv, sa[0][ct], 0, 0, 0);
        sa[1][ct] = __builtin_amdgcn_mfma_f32_16x16x32_bf16(a2[1], bv, sa[1][ct], 0, 0, 0);
    }
    __syncthreads();

    if (storeG) {
        #pragma unroll
        for (int r = 0; r < 4; ++r) {
            int e = t + 256 * r;
            int row = e >> 3, oct = e & 7;
            int sw = (oct + row + (row >> 5)) & 7;
            us8 v = *(const us8*)(Hs + row * 72 + sw * 8);
            *(us8*)(G + ((size_t)(b * 32 + (row >> 2)) * 512 + n0 + (row & 3)) * 64 + oct * 8) = v;
        }
    }
    __syncthreads();

    float* St = (float*)Hs;
    const float rbn = rsqrtf(1.f + 1e-5f);
    #pragma unroll
    for (int half = 0; half < 2; ++half) {
        if ((w >> 1) == half) {
            #pragma unroll
            for (int mt = 0; mt < 2; ++mt)
                #pragma unroll
                for (int ct = 0; ct < 4; ++ct) {
                    int col = (w & 1) * 64 + ct * 16 + la;
                    int ob = mt * 16 + q * 4;
                    float4 sv = make_float4(sa[mt][ct][0] + bsv[ob],
                                            sa[mt][ct][1] + bsv[ob + 1],
                                            sa[mt][ct][2] + bsv[ob + 2],
                                            sa[mt][ct][3] + bsv[ob + 3]);
                    *(float4*)(St + col * 36 + ob) = sv;
                }
        }
        __syncthreads();
        {
            int col = t >> 1, o0 = (t & 1) * 16;
            int nr = half * 2 + (col >> 6), l = col & 63;
            if (l < LOUT_) {
                float* po = out + ((size_t)(b * LOUT_ + l) * 512 + n0 + nr) * 32 + o0;
                #pragma unroll
                for (int i = 0; i < 4; ++i) {
                    float4 s = *(float4*)(St + col * 36 + o0 + i * 4);
                    if (mode == 0) {
                        *(float4*)(po + i * 4) = s;
                    } else {
                        float4 old = *(float4*)(po + i * 4);
                        float4 vv = make_float4(old.x + s.x, old.y + s.y,
                                                old.z + s.z, old.w + s.w);
                        if (mode == 2) {
                            int ob = o0 + i * 4;
                            vv.x = vv.x * (og[ob] * rbn) + obb[ob];
                            vv.y = vv.y * (og[ob + 1] * rbn) + obb[ob + 1];
                            vv.z = vv.z * (og[ob + 2] * rbn) + obb[ob + 2];
                            vv.w = vv.w * (og[ob + 3] * rbn) + obb[ob + 3];
                        }
                        *(float4*)(po + i * 4) = vv;
                    }
                }
            }
        }
        __syncthreads();
    }
}

// ---------------- K3: dual MFMA diffusion: x1 = G.adj, x2 = G.adj2 in one pass
__global__ __launch_bounds__(256, 2) void k_diffuse2(
        const ushort_t* __restrict__ X, const ushort_t* __restrict__ adjT,
        const ushort_t* __restrict__ adj2T,
        ushort_t* __restrict__ Y1, ushort_t* __restrict__ Y2) {
    __shared__ __align__(16) ushort_t lds[16384];  // As1|As2|Xs; Ys aliases
    ushort_t* As1 = lds;
    ushort_t* As2 = lds + 4096;
    ushort_t* Xs  = lds + 8192;
    int cp = blockIdx.x & 15;          // c-pair (2 channels)
    int mt = (blockIdx.x >> 4) & 7;
    int b  = blockIdx.x >> 7;
    int t  = threadIdx.x;
    int lane = t & 63, w = t >> 6;
    int c_loc = w & 1, lh = w >> 1;
    int m0 = mt * 64;
    int la = lane & 15, q = lane >> 4;
    const ushort_t* Xb = X + (size_t)(b * 32 + cp * 2) * 512 * 64;
    f32x4 acc1[4][2], acc2[4][2];
    #pragma unroll
    for (int mi = 0; mi < 4; ++mi)
        #pragma unroll
        for (int li = 0; li < 2; ++li) { acc1[mi][li] = (f32x4)0.f; acc2[mi][li] = (f32x4)0.f; }

    for (int n0 = 0; n0 < 512; n0 += 64) {
        __syncthreads();
        #pragma unroll
        for (int r = 0; r < 2; ++r) {
            int e = t + 256 * r;
            int ml = e >> 3, oct = e & 7;
            int sw = ((oct + (ml >> 3)) & 7) << 3;
            *(us8*)(As1 + ml * 64 + sw) =
                *(const us8*)(adjT + (size_t)(m0 + ml) * 512 + n0 + oct * 8);
            *(us8*)(As2 + ml * 64 + sw) =
                *(const us8*)(adj2T + (size_t)(m0 + ml) * 512 + n0 + oct * 8);
        }
        #pragma unroll
        for (int r = 0; r < 4; ++r) {
            int e = t + 256 * r;
            int cl = e >> 9, nl = (e >> 3) & 63, oct = e & 7;
            us8 v = *(const us8*)(Xb + ((size_t)cl * 512 + n0 + nl) * 64 + oct * 8);
            *(us8*)(Xs + cl * 4096 + nl * 64 + (((oct + (nl >> 3)) & 7) << 3)) = v;
        }
        __syncthreads();
        #pragma unroll
        for (int ks = 0; ks < 2; ++ks) {
            bf16x8 a1[4], a2v[4];
            #pragma unroll
            for (int mi = 0; mi < 4; ++mi) {
                int m = mi * 16 + la;
                int bl = (ks * 4 + q + (m >> 3)) & 7;
                a1[mi]  = *(const bf16x8*)(As1 + m * 64 + bl * 8);
                a2v[mi] = *(const bf16x8*)(As2 + m * 64 + bl * 8);
            }
            bf16x8 bb[2];
            #pragma unroll
            for (int li = 0; li < 2; ++li) {
                int l = lh * 32 + li * 16 + la;
                int rot = ((l >> 3) + ks * 4 + q) & 7;
                int col = rot * 8 + (l & 7);
                const ushort_t* p = Xs + c_loc * 4096 + (ks * 32 + q * 8) * 64 + col;
                bf16x8 v;
                #pragma unroll
                for (int j = 0; j < 8; ++j) v[j] = (short)p[j * 64];
                bb[li] = v;
            }
            #pragma unroll
            for (int mi = 0; mi < 4; ++mi)
                #pragma unroll
                for (int li = 0; li < 2; ++li) {
                    acc1[mi][li] = __builtin_amdgcn_mfma_f32_16x16x32_bf16(a1[mi], bb[li], acc1[mi][li], 0, 0, 0);
                    acc2[mi][li] = __builtin_amdgcn_mfma_f32_16x16x32_bf16(a2v[mi], bb[li], acc2[mi][li], 0, 0, 0);
                }
        }
    }
    ushort_t* Ys = lds;                            // [2][64][72]
    #pragma unroll
    for (int pass = 0; pass < 2; ++pass) {
        __syncthreads();
        f32x4 (*src)[2] = pass ? acc2 : acc1;
        #pragma unroll
        for (int mi = 0; mi < 4; ++mi)
            #pragma unroll
            for (int li = 0; li < 2; ++li)
                #pragma unroll
                for (int r = 0; r < 4; ++r) {
                    int row = mi * 16 + q * 4 + r;
                    int col = lh * 32 + li * 16 + la;
                    Ys[c_loc * 4608 + row * 72 + col] = f2bits(src[mi][li][r]);
                }
        __syncthreads();
        ushort_t* Yo = pass ? Y2 : Y1;
        int c = t >> 7, mrem = t & 127;
        int m = mrem >> 1, lq = mrem & 1;
        #pragma unroll
        for (int r = 0; r < 4; ++r) {
            int l0 = lq * 32 + r * 8;
            us8 v = *(const us8*)(Ys + c * 4608 + m * 72 + l0);
            *(us8*)(Yo + ((size_t)(b * 32 + cp * 2 + c) * 512 + m0 + m) * 64 + l0) = v;
        }
    }
}

// ---------------- K4: MFMA graph-conv(96->32) + gcBN + residual + BN, in place over G.
// Block = (b, 4-node chunk); wave w = node. GEMM [32o x 96k] x [96k x 64l].
__global__ __launch_bounds__(256, 2) void k_gc3_mfma(
        ushort_t* __restrict__ G, const ushort_t* __restrict__ X1,
        const ushort_t* __restrict__ X2, const ushort_t* __restrict__ hres,
        const float* __restrict__ Wgc, const float* __restrict__ bgc,
        const float* __restrict__ gg, const float* __restrict__ gb,
        const float* __restrict__ bg2, const float* __restrict__ bb2) {
    __shared__ __align__(16) ushort_t cat[384 * 72];   // B rows k*4+nr; reused as out tile
    __shared__ __align__(16) ushort_t hr[128 * 64];    // hres tile, plain stride 64
    __shared__ __align__(16) ushort_t Aw[32 * 104];    // Wgc bf16 [o][96]
    __shared__ float prm[5][32];                       // bgc, gg, gb, bg2, bb2
    int t = threadIdx.x;
    int b = blockIdx.x >> 7, n0 = (blockIdx.x & 127) * 4;
    int lane = t & 63, w = t >> 6;     // wave w = node nr
    int la = lane & 15, q = lane >> 4;

    #pragma unroll
    for (int r = 0; r < 12; ++r) {                 // stage cat: 3072 us8
        int e = t + 256 * r;
        int row = e >> 3, oct = e & 7;
        int k = row >> 2;
        const ushort_t* src = (k < 32) ? G : ((k < 64) ? X1 : X2);
        us8 v = *(const us8*)(src + ((size_t)(b * 32 + (k & 31)) * 512 + n0 + (row & 3)) * 64 + oct * 8);
        int sw = (oct + row + (row >> 5)) & 7;
        *(us8*)(cat + row * 72 + sw * 8) = v;
    }
    #pragma unroll
    for (int r = 0; r < 4; ++r) {                  // stage hres: 1024 us8
        int e = t + 256 * r;
        int row = e >> 3, oct = e & 7;
        us8 v = *(const us8*)(hres + ((size_t)(b * 32 + (row >> 2)) * 512 + n0 + (row & 3)) * 64 + oct * 8);
        *(us8*)(hr + row * 64 + oct * 8) = v;
    }
    for (int e = t; e < 384; e += 256) {           // stage weights fp32->bf16
        int o = e / 12, oct = e % 12;
        us8 v;
        #pragma unroll
        for (int i = 0; i < 8; ++i) v[i] = f2bits(Wgc[o * 96 + oct * 8 + i]);
        *(us8*)(Aw + o * 104 + oct * 8) = v;
    }
    if (t < 32) {
        prm[0][t] = bgc[t]; prm[1][t] = gg[t]; prm[2][t] = gb[t];
        prm[3][t] = bg2[t]; prm[4][t] = bb2[t];
    }
    __syncthreads();

    bf16x8 a[2][3];
    #pragma unroll
    for (int mt = 0; mt < 2; ++mt)
        #pragma unroll
        for (int ks = 0; ks < 3; ++ks)
            a[mt][ks] = *(const bf16x8*)(Aw + (mt * 16 + la) * 104 + ks * 32 + q * 8);

    f32x4 acc[2][4];
    #pragma unroll
    for (int mt = 0; mt < 2; ++mt)
        #pragma unroll
        for (int ct = 0; ct < 4; ++ct) acc[mt][ct] = (f32x4)0.f;
    #pragma unroll
    for (int ct = 0; ct < 4; ++ct) {
        int le = ct * 16 + la;
        #pragma unroll
        for (int ks = 0; ks < 3; ++ks) {
            bf16x8 bv;
            #pragma unroll
            for (int j = 0; j < 8; ++j) {
                int row = (ks * 32 + q * 8 + j) * 4 + w;
                int sw = ((le >> 3) + row + (row >> 5)) & 7;
                bv[j] = (short)cat[row * 72 + sw * 8 + (le & 7)];
            }
            acc[0][ct] = __builtin_amdgcn_mfma_f32_16x16x32_bf16(a[0][ks], bv, acc[0][ct], 0, 0, 0);
            acc[1][ct] = __builtin_amdgcn_mfma_f32_16x16x32_bf16(a[1][ks], bv, acc[1][ct], 0, 0, 0);
        }
    }
    __syncthreads();                               // all B reads done; reuse cat as out tile

    const float rbn = rsqrtf(1.f + 1e-5f);
    #pragma unroll
    for (int mt = 0; mt < 2; ++mt)
        #pragma unroll
        for (int ct = 0; ct < 4; ++ct)
            #pragma unroll
            for (int r = 0; r < 4; ++r) {
                int o = mt * 16 + q * 4 + r;
                int l = ct * 16 + la;
                float v = acc[mt][ct][r] + prm[0][o];
                v = v * (prm[1][o] * rbn) + prm[2][o];
                float res = (l < 63) ? bits2f(hr[(o * 4 + w) * 64 + l + 1]) : 0.f;
                v = (v + res) * (prm[3][o] * rbn) + prm[4][o];
                int row = o * 4 + w;
                int sw = ((l >> 3) + row + (row >> 5)) & 7;
                cat[row * 72 + sw * 8 + (l & 7)] = f2bits(v);
            }
    __syncthreads();
    #pragma unroll
    for (int r = 0; r < 4; ++r) {
        int e = t + 256 * r;
        int row = e >> 3, oct = e & 7;
        int sw = (oct + row + (row >> 5)) & 7;
        us8 v = *(const us8*)(cat + row * 72 + sw * 8);
        *(us8*)(G + ((size_t)(b * 32 + (row >> 2)) * 512 + n0 + (row & 3)) * 64 + oct * 8) = v;
    }
}

extern "C" void kernel_launch(void* const* d_in, const int* in_sizes, int n_in,
                              void* d_out, int out_size, void* d_ws, size_t ws_size,
                              hipStream_t stream) {
    const float* x      = (const float*)d_in[0];
    const float* adj    = (const float*)d_in[1];
    const float* Wstart = (const float*)d_in[2];
    const float* bstart = (const float*)d_in[3];
    const float* Wf     = (const float*)d_in[4];
    const float* bf_    = (const float*)d_in[5];
    const float* Wg     = (const float*)d_in[6];
    const float* bg     = (const float*)d_in[7];
    const float* Wskip  = (const float*)d_in[8];
    const float* bskip  = (const float*)d_in[9];
    const float* Wgc    = (const float*)d_in[10];
    const float* bgc    = (const float*)d_in[11];
    const float* gcbn_g = (const float*)d_in[12];
    const float* gcbn_b = (const float*)d_in[13];
    const float* bn_g   = (const float*)d_in[14];
    const float* bn_b   = (const float*)d_in[15];
    const float* obn_g  = (const float*)d_in[16];
    const float* obn_b  = (const float*)d_in[17];
    float* out = (float*)d_out;

    // 4 bf16 scratch buffers (64 MiB) + adjT + adj2T (512 KiB each)
    ushort_t* P0    = (ushort_t*)d_ws;
    ushort_t* P1    = P0 + BUF_;
    ushort_t* P2    = P1 + BUF_;
    ushort_t* P3    = P2 + BUF_;
    ushort_t* adjT  = P3 + BUF_;
    ushort_t* adj2T = adjT + 512 * 512;

    k_transA<<<64, 256, 0, stream>>>(adj, adjT);
    k_sq<<<64, 256, 0, stream>>>(adjT, adj2T);
    k_start<<<4096, 256, 0, stream>>>(x, Wstart, bstart, P0);

    ushort_t* h  = P0;
    ushort_t* Gb = P1;
    for (int i = 0; i < 3; ++i) {
        int mode = (i == 0) ? 0 : ((i == 2) ? 2 : 1);
        k_gs_mfma<<<1024, 256, 0, stream>>>(h, Wf + i * 2048, bf_ + i * 32,
                                            Wg + i * 2048, bg + i * 32,
                                            Wskip + i * 1024, bskip + i * 32,
                                            Gb, out, 2 - i, mode, (i < 2) ? 1 : 0,
                                            obn_g, obn_b);
        if (i == 2) break;
        k_diffuse2<<<1024, 256, 0, stream>>>(Gb, adjT, adj2T, P2, P3);  // x1, x2
        k_gc3_mfma<<<1024, 256, 0, stream>>>(Gb, P2, P3, h,
                                             Wgc + i * 3072, bgc + i * 32,
                                             gcbn_g + i * 32, gcbn_b + i * 32,
                                             bn_g + i * 32, bn_b + i * 32);
        ushort_t* tmp = h; h = Gb; Gb = tmp;   // new h lives where G was
    }
}